// Round 1
// baseline (595.936 us; speedup 1.0000x reference)
//
#include <hip/hip_runtime.h>

#define NN 10000      // nodes
#define NE 320000     // edges (before self-loops)
#define NB 64         // graphs
#define CIN 128       // in_channels
#define CEC 64        // edge_channels
#define CHID 256      // hidden
#define CMLP 512
#define CNC 4

static __host__ int cdiv(int a, int b) { return (a + b - 1) / b; }

// ---------------- setup kernels ----------------

__global__ __launch_bounds__(256) void k_init(int* __restrict__ ptr, float* __restrict__ pooled,
                                              float* __restrict__ counts, float* __restrict__ colsum,
                                              float* __restrict__ colsq) {
  int i = blockIdx.x * 256 + threadIdx.x;
  if (i <= NN) ptr[i] = 0;
  if (i < NB * CHID) pooled[i] = 0.f;
  if (i < NB) counts[i] = 0.f;
  if (i < CHID) { colsum[i] = 0.f; colsq[i] = 0.f; }
}

__global__ __launch_bounds__(256) void k_count(const int* __restrict__ ei, int* __restrict__ ptr) {
  int e = blockIdx.x * 256 + threadIdx.x;
  if (e < NE) atomicAdd(&ptr[ei[NE + e] + 1], 1);
}

// single-block inclusive scan over ptr[0..NN]
__global__ __launch_bounds__(1024) void k_scan(int* __restrict__ ptr) {
  __shared__ int buf[1024];
  int carry = 0;
  const int n1 = NN + 1;
  for (int base = 0; base < n1; base += 1024) {
    int i = base + threadIdx.x;
    int v = (i < n1) ? ptr[i] : 0;
    buf[threadIdx.x] = v;
    __syncthreads();
    for (int offm = 1; offm < 1024; offm <<= 1) {
      int t = (threadIdx.x >= offm) ? buf[threadIdx.x - offm] : 0;
      __syncthreads();
      buf[threadIdx.x] += t;
      __syncthreads();
    }
    if (i < n1) ptr[i] = buf[threadIdx.x] + carry;
    int tot = buf[1023];
    __syncthreads();
    carry += tot;
  }
}

__global__ __launch_bounds__(256) void k_degpos(const int* __restrict__ ptr, int* __restrict__ pos,
                                                float* __restrict__ degf) {
  int i = blockIdx.x * 256 + threadIdx.x;
  if (i < NN) {
    pos[i] = ptr[i];
    degf[i] = (float)(ptr[i + 1] - ptr[i] + 1);  // +1 self-loop
  }
}

__global__ __launch_bounds__(256) void k_fill(const int* __restrict__ ei, int* __restrict__ pos,
                                              int* __restrict__ eid, int* __restrict__ srcs) {
  int e = blockIdx.x * 256 + threadIdx.x;
  if (e < NE) {
    int d = ei[NE + e];
    int idx = atomicAdd(&pos[d], 1);
    eid[idx] = e;
    srcs[idx] = ei[e];
  }
}

// ea_sum[i][c] = 1 + sum of edge_attr over incoming edges
__global__ __launch_bounds__(64) void k_ea(const float* __restrict__ eattr, const int* __restrict__ ptr,
                                           const int* __restrict__ eid, float* __restrict__ ea) {
  __shared__ int sidx[64];
  int i = blockIdx.x;
  int c = threadIdx.x;
  int s = ptr[i], e = ptr[i + 1];
  float acc = 1.0f;  // PyG self-loop edge_attr fill = 1.0
  for (int k0 = s; k0 < e; k0 += 64) {
    int nload = min(64, e - k0);
    if (c < nload) sidx[c] = eid[k0 + c];
    __syncthreads();
    for (int k = 0; k < nload; ++k) acc += eattr[sidx[k] * CEC + c];
    __syncthreads();
  }
  ea[i * CEC + c] = acc;
}

// ---------------- per-layer kernels ----------------

// G[i] = h[i] + sum over incoming edges of h[src]
__global__ void k_gather(const float* __restrict__ h, const int* __restrict__ ptr,
                         const int* __restrict__ srcs, float* __restrict__ G, int Kh) {
  __shared__ int sidx[128];
  int i = blockIdx.x;
  int c = threadIdx.x;  // blockDim == Kh
  int s = ptr[i], e = ptr[i + 1];
  float acc = h[i * Kh + c];
  for (int k0 = s; k0 < e; k0 += 128) {
    int nload = min(128, e - k0);
    if (c < nload) sidx[c] = srcs[k0 + c];
    __syncthreads();
    for (int k = 0; k < nload; ++k) acc += h[sidx[k] * Kh + c];
    __syncthreads();
  }
  G[i * Kh + c] = acc;
}

// fused GEMM: out[i][o] = relu( degf_i*(h_i@Wd + b) + G_i@Ws + ea_i@We )
// virtual A row i = [degf_i*h_i (Kh) | G_i (Kh) | ea_i (64)], Kdim = 2*Kh+64
__global__ __launch_bounds__(256) void k_gemm(const float* __restrict__ h, const float* __restrict__ G,
                                              const float* __restrict__ ea, const float* __restrict__ degf,
                                              const float* __restrict__ W, const float* __restrict__ bias,
                                              float* __restrict__ out, int Kh) {
  const int Kdim = 2 * Kh + CEC;
  __shared__ float As[16][68];  // [k][m], stride 68 keeps float4 alignment
  __shared__ float Bs[16][68];
  const int bm = blockIdx.x * 64;
  const int bn = blockIdx.y * 64;
  const int tid = threadIdx.x;
  const int tm = (tid >> 4) << 2;
  const int tn = (tid & 15) << 2;
  float acc[4][4] = {};

  const int mA = tid >> 2;          // 0..63
  const int kA = (tid & 3) << 2;    // 0,4,8,12
  const int rowA = bm + mA;
  const int nB = tid & 63;
  const int kB = tid >> 6;          // 0..3

  for (int k0 = 0; k0 < Kdim; k0 += 16) {
    float4 av = make_float4(0.f, 0.f, 0.f, 0.f);
    if (rowA < NN) {
      int kg = k0 + kA;
      if (kg < Kh) {
        av = *(const float4*)&h[rowA * Kh + kg];
        float d = degf[rowA];
        av.x *= d; av.y *= d; av.z *= d; av.w *= d;
      } else if (kg < 2 * Kh) {
        av = *(const float4*)&G[rowA * Kh + (kg - Kh)];
      } else {
        av = *(const float4*)&ea[rowA * CEC + (kg - 2 * Kh)];
      }
    }
    As[kA + 0][mA] = av.x;
    As[kA + 1][mA] = av.y;
    As[kA + 2][mA] = av.z;
    As[kA + 3][mA] = av.w;
#pragma unroll
    for (int s = 0; s < 4; ++s) {
      int kk = kB + (s << 2);
      Bs[kk][nB] = W[(k0 + kk) * CHID + bn + nB];
    }
    __syncthreads();
#pragma unroll
    for (int kk = 0; kk < 16; ++kk) {
      float4 a = *(const float4*)&As[kk][tm];
      float4 b = *(const float4*)&Bs[kk][tn];
      acc[0][0] += a.x * b.x; acc[0][1] += a.x * b.y; acc[0][2] += a.x * b.z; acc[0][3] += a.x * b.w;
      acc[1][0] += a.y * b.x; acc[1][1] += a.y * b.y; acc[1][2] += a.y * b.z; acc[1][3] += a.y * b.w;
      acc[2][0] += a.z * b.x; acc[2][1] += a.z * b.y; acc[2][2] += a.z * b.z; acc[2][3] += a.z * b.w;
      acc[3][0] += a.w * b.x; acc[3][1] += a.w * b.y; acc[3][2] += a.w * b.z; acc[3][3] += a.w * b.w;
    }
    __syncthreads();
  }
#pragma unroll
  for (int i = 0; i < 4; ++i) {
    int row = bm + tm + i;
    if (row < NN) {
      float d = degf[row];
#pragma unroll
      for (int j = 0; j < 4; ++j) {
        out[row * CHID + bn + tn + j] = fmaxf(acc[i][j] + d * bias[bn + tn + j], 0.f);
      }
    }
  }
}

__global__ __launch_bounds__(256) void k_stats(const float* __restrict__ t, float* __restrict__ colsum,
                                               float* __restrict__ colsq) {
  int c = threadIdx.x;
  int r0 = blockIdx.x * 64;
  int rows = min(64, NN - r0);
  float s = 0.f, q = 0.f;
  for (int r = 0; r < rows; ++r) {
    float v = t[(r0 + r) * CHID + c];
    s += v; q += v * v;
  }
  atomicAdd(&colsum[c], s);
  atomicAdd(&colsq[c], q);
}

__global__ __launch_bounds__(256) void k_bnfin(float* __restrict__ colsum, float* __restrict__ colsq,
                                               const float* __restrict__ g, const float* __restrict__ be,
                                               float* __restrict__ scale, float* __restrict__ shift) {
  int c = threadIdx.x;
  float mu = colsum[c] / (float)NN;
  float var = colsq[c] / (float)NN - mu * mu;
  float inv = rsqrtf(var + 1e-5f);
  float sc = g[c] * inv;
  scale[c] = sc;
  shift[c] = be[c] - mu * sc;
  colsum[c] = 0.f;  // ready for next layer
  colsq[c] = 0.f;
}

__global__ __launch_bounds__(256) void k_bnapply(const float* __restrict__ t, const float* __restrict__ scale,
                                                 const float* __restrict__ shift, float* __restrict__ h) {
  int i = blockIdx.x * 256 + threadIdx.x;
  if (i < NN * CHID) {
    int c = i & (CHID - 1);
    h[i] = fmaxf(fmaf(t[i], scale[c], shift[c]), 0.f);
  }
}

// ---------------- pooling + MLP ----------------

__global__ __launch_bounds__(256) void k_pool(const float* __restrict__ h, const int* __restrict__ batch,
                                              float* __restrict__ pooled, float* __restrict__ counts) {
  __shared__ int bsh[64];
  int r0 = blockIdx.x * 64;
  int c = threadIdx.x;
  int rows = min(64, NN - r0);
  if (c < rows) bsh[c] = batch[r0 + c];
  __syncthreads();
  float acc = 0.f;
  int cur = bsh[0];
  for (int r = 0; r < rows; ++r) {
    int g = bsh[r];
    if (g != cur) {
      atomicAdd(&pooled[cur * CHID + c], acc);
      acc = 0.f;
      cur = g;
    }
    acc += h[(r0 + r) * CHID + c];
  }
  atomicAdd(&pooled[cur * CHID + c], acc);
  if (c == 0) {
    int cur2 = bsh[0], cnt = 0;
    for (int r = 0; r < rows; ++r) {
      if (bsh[r] != cur2) {
        atomicAdd(&counts[cur2], (float)cnt);
        cur2 = bsh[r]; cnt = 0;
      }
      cnt++;
    }
    atomicAdd(&counts[cur2], (float)cnt);
  }
}

__global__ __launch_bounds__(512) void k_mlp(const float* __restrict__ pooled, const float* __restrict__ counts,
                                             const float* __restrict__ nb, const float* __restrict__ w1,
                                             const float* __restrict__ b1, const float* __restrict__ w2,
                                             const float* __restrict__ b2, float* __restrict__ out) {
  int g = blockIdx.x;
  int t = threadIdx.x;
  __shared__ float zin[CHID + 1 + CIN];  // 385
  __shared__ float red[512];
  if (t < CHID) zin[t] = pooled[g * CHID + t];
  else if (t == CHID) zin[CHID] = counts[g] * 0.025f;  // / MAX_SIZE(40)
  else if (t < CHID + 1 + CIN) zin[t] = nb[g * CIN + (t - CHID - 1)];
  __syncthreads();
  float acc = b1[t];
  for (int k = 0; k < CHID + 1 + CIN; ++k) acc = fmaf(zin[k], w1[k * CMLP + t], acc);
  float z = fmaxf(acc, 0.f);
#pragma unroll
  for (int n = 0; n < CNC; ++n) {
    red[t] = z * w2[t * CNC + n];
    __syncthreads();
    for (int s = 256; s > 0; s >>= 1) {
      if (t < s) red[t] += red[t + s];
      __syncthreads();
    }
    if (t == 0) out[g * CNC + n] = red[0] + b2[n];
    __syncthreads();
  }
}

// ---------------- launch ----------------

extern "C" void kernel_launch(void* const* d_in, const int* in_sizes, int n_in,
                              void* d_out, int out_size, void* d_ws, size_t ws_size,
                              hipStream_t stream) {
  const float* x     = (const float*)d_in[0];
  const int*   ei    = (const int*)d_in[1];
  const float* eattr = (const float*)d_in[2];
  const int*   batch = (const int*)d_in[3];
  const float* nbr   = (const float*)d_in[4];
  const float* W1 = (const float*)d_in[5];
  const float* b1 = (const float*)d_in[6];
  const float* g1 = (const float*)d_in[7];
  const float* be1 = (const float*)d_in[8];
  const float* W2 = (const float*)d_in[9];
  const float* b2 = (const float*)d_in[10];
  const float* g2 = (const float*)d_in[11];
  const float* be2 = (const float*)d_in[12];
  const float* W3 = (const float*)d_in[13];
  const float* b3 = (const float*)d_in[14];
  const float* g3 = (const float*)d_in[15];
  const float* be3 = (const float*)d_in[16];
  const float* fc1w = (const float*)d_in[17];
  const float* fc1b = (const float*)d_in[18];
  const float* fc2w = (const float*)d_in[19];
  const float* fc2b = (const float*)d_in[20];
  float* out = (float*)d_out;

  char* ws = (char*)d_ws;
  size_t off = 0;
  auto alloc = [&](size_t bytes) {
    void* p = ws + off;
    off = (off + bytes + 255) & ~(size_t)255;
    return p;
  };
  int*   ptr    = (int*)alloc((NN + 1) * sizeof(int));
  int*   pos    = (int*)alloc(NN * sizeof(int));
  float* degf   = (float*)alloc(NN * sizeof(float));
  int*   eid    = (int*)alloc(NE * sizeof(int));
  int*   srcs   = (int*)alloc(NE * sizeof(int));
  float* ea     = (float*)alloc((size_t)NN * CEC * sizeof(float));
  float* G      = (float*)alloc((size_t)NN * CHID * sizeof(float));
  float* tmp    = (float*)alloc((size_t)NN * CHID * sizeof(float));
  float* h      = (float*)alloc((size_t)NN * CHID * sizeof(float));
  float* colsum = (float*)alloc(CHID * sizeof(float));
  float* colsq  = (float*)alloc(CHID * sizeof(float));
  float* scale  = (float*)alloc(CHID * sizeof(float));
  float* shift  = (float*)alloc(CHID * sizeof(float));
  float* pooled = (float*)alloc((size_t)NB * CHID * sizeof(float));
  float* counts = (float*)alloc(NB * sizeof(float));
  (void)ws_size; (void)n_in; (void)in_sizes; (void)out_size;

  // build CSR + static aggregates
  k_init<<<cdiv(NB * CHID, 256), 256, 0, stream>>>(ptr, pooled, counts, colsum, colsq);
  k_count<<<cdiv(NE, 256), 256, 0, stream>>>(ei, ptr);
  k_scan<<<1, 1024, 0, stream>>>(ptr);
  k_degpos<<<cdiv(NN, 256), 256, 0, stream>>>(ptr, pos, degf);
  k_fill<<<cdiv(NE, 256), 256, 0, stream>>>(ei, pos, eid, srcs);
  k_ea<<<NN, 64, 0, stream>>>(eattr, ptr, eid, ea);

  dim3 ggrid(cdiv(NN, 64), CHID / 64);

  // layer 1 (Kh = CIN)
  k_gather<<<NN, CIN, 0, stream>>>(x, ptr, srcs, G, CIN);
  k_gemm<<<ggrid, 256, 0, stream>>>(x, G, ea, degf, W1, b1, tmp, CIN);
  k_stats<<<cdiv(NN, 64), 256, 0, stream>>>(tmp, colsum, colsq);
  k_bnfin<<<1, 256, 0, stream>>>(colsum, colsq, g1, be1, scale, shift);
  k_bnapply<<<cdiv(NN * CHID, 256), 256, 0, stream>>>(tmp, scale, shift, h);

  // layer 2
  k_gather<<<NN, CHID, 0, stream>>>(h, ptr, srcs, G, CHID);
  k_gemm<<<ggrid, 256, 0, stream>>>(h, G, ea, degf, W2, b2, tmp, CHID);
  k_stats<<<cdiv(NN, 64), 256, 0, stream>>>(tmp, colsum, colsq);
  k_bnfin<<<1, 256, 0, stream>>>(colsum, colsq, g2, be2, scale, shift);
  k_bnapply<<<cdiv(NN * CHID, 256), 256, 0, stream>>>(tmp, scale, shift, h);

  // layer 3
  k_gather<<<NN, CHID, 0, stream>>>(h, ptr, srcs, G, CHID);
  k_gemm<<<ggrid, 256, 0, stream>>>(h, G, ea, degf, W3, b3, tmp, CHID);
  k_stats<<<cdiv(NN, 64), 256, 0, stream>>>(tmp, colsum, colsq);
  k_bnfin<<<1, 256, 0, stream>>>(colsum, colsq, g3, be3, scale, shift);
  k_bnapply<<<cdiv(NN * CHID, 256), 256, 0, stream>>>(tmp, scale, shift, h);

  // pool + MLP head
  k_pool<<<cdiv(NN, 64), 256, 0, stream>>>(h, batch, pooled, counts);
  k_mlp<<<NB, 512, 0, stream>>>(pooled, counts, nbr, fc1w, fc1b, fc2w, fc2b, out);
}

// Round 2
// 565.310 us; speedup vs baseline: 1.0542x; 1.0542x over previous
//
#include <hip/hip_runtime.h>

#define NN 10000      // nodes
#define NE 320000     // edges (before self-loops)
#define NB 64         // graphs
#define CIN 128       // in_channels
#define CEC 64        // edge_channels
#define CHID 256      // hidden
#define CMLP 512
#define CNC 4
#define K1 (2 * CIN + CEC)    // 320
#define K23 (2 * CHID + CEC)  // 576

static __host__ int cdiv(int a, int b) { return (a + b - 1) / b; }

typedef short sfrag __attribute__((ext_vector_type(8)));   // 8 bf16 in 4 VGPRs
typedef float f4 __attribute__((ext_vector_type(4)));

static __device__ __forceinline__ ushort f2b(float f) {
  union { float f; unsigned u; } v; v.f = f;
  unsigned r = (v.u + 0x7fffu + ((v.u >> 16) & 1u)) >> 16;
  return (ushort)r;
}

// ---------------- setup kernels ----------------

__global__ __launch_bounds__(256) void k_init(int* __restrict__ ptr, float* __restrict__ pooled,
                                              float* __restrict__ counts, float* __restrict__ colsum,
                                              float* __restrict__ colsq) {
  int i = blockIdx.x * 256 + threadIdx.x;
  if (i <= NN) ptr[i] = 0;
  if (i < NB * CHID) pooled[i] = 0.f;
  if (i < NB) counts[i] = 0.f;
  if (i < CHID) { colsum[i] = 0.f; colsq[i] = 0.f; }
}

__global__ __launch_bounds__(256) void k_count(const int* __restrict__ ei, int* __restrict__ ptr) {
  int e = blockIdx.x * 256 + threadIdx.x;
  if (e < NE) atomicAdd(&ptr[ei[NE + e] + 1], 1);
}

// single-block inclusive scan over ptr[0..NN]
__global__ __launch_bounds__(1024) void k_scan(int* __restrict__ ptr) {
  __shared__ int buf[1024];
  int carry = 0;
  const int n1 = NN + 1;
  for (int base = 0; base < n1; base += 1024) {
    int i = base + threadIdx.x;
    int v = (i < n1) ? ptr[i] : 0;
    buf[threadIdx.x] = v;
    __syncthreads();
    for (int offm = 1; offm < 1024; offm <<= 1) {
      int t = (threadIdx.x >= offm) ? buf[threadIdx.x - offm] : 0;
      __syncthreads();
      buf[threadIdx.x] += t;
      __syncthreads();
    }
    if (i < n1) ptr[i] = buf[threadIdx.x] + carry;
    int tot = buf[1023];
    __syncthreads();
    carry += tot;
  }
}

__global__ __launch_bounds__(256) void k_degpos(const int* __restrict__ ptr, int* __restrict__ pos,
                                                float* __restrict__ degf) {
  int i = blockIdx.x * 256 + threadIdx.x;
  if (i < NN) {
    pos[i] = ptr[i];
    degf[i] = (float)(ptr[i + 1] - ptr[i] + 1);  // +1 self-loop
  }
}

__global__ __launch_bounds__(256) void k_fill(const int* __restrict__ ei, int* __restrict__ pos,
                                              int* __restrict__ eid, int* __restrict__ srcs) {
  int e = blockIdx.x * 256 + threadIdx.x;
  if (e < NE) {
    int d = ei[NE + e];
    int idx = atomicAdd(&pos[d], 1);
    eid[idx] = e;
    srcs[idx] = ei[e];
  }
}

// ea_sum[i][c] = 1 + sum of incoming edge_attr; bf16 into both A panels
__global__ __launch_bounds__(256) void k_ea(const float* __restrict__ eattr, const int* __restrict__ ptr,
                                            const int* __restrict__ eid, ushort* __restrict__ A1,
                                            ushort* __restrict__ A23) {
  int node = blockIdx.x * 4 + (threadIdx.x >> 6);
  int lane = threadIdx.x & 63;
  int s = ptr[node], e = ptr[node + 1];
  float acc = 1.0f;  // PyG self-loop edge_attr fill
  for (int k = s; k < e; ++k) {
    int idx = eid[k];
    acc += eattr[(size_t)idx * CEC + lane];
  }
  ushort b = f2b(acc);
  A1[(size_t)node * K1 + 2 * CIN + lane] = b;
  A23[(size_t)node * K23 + 2 * CHID + lane] = b;
}

// A1[:, 0:128] = bf16(degf * x)
__global__ __launch_bounds__(256) void k_prep(const float4* __restrict__ x, const float* __restrict__ degf,
                                              ushort* __restrict__ A1) {
  int gid = blockIdx.x * 256 + threadIdx.x;  // NN*32
  if (gid >= NN * (CIN / 4)) return;
  int node = gid >> 5;
  int c4 = (gid & 31) << 2;
  float d = degf[node];
  float4 v = x[gid];
  ushort4 o = { f2b(d * v.x), f2b(d * v.y), f2b(d * v.z), f2b(d * v.w) };
  *(ushort4*)&A1[(size_t)node * K1 + c4] = o;
}

// ---------------- gathers (wave per node) ----------------

// layer 1: G from x (Kh=128) -> A1[:, 128:256]
__global__ __launch_bounds__(256) void k_gather128(const float2* __restrict__ h, const int* __restrict__ ptr,
                                                   const int* __restrict__ srcs, ushort* __restrict__ A1) {
  int node = blockIdx.x * 4 + (threadIdx.x >> 6);
  int lane = threadIdx.x & 63;
  float2 acc = h[(size_t)node * 64 + lane];
  int s = ptr[node], e = ptr[node + 1];
  for (int k = s; k < e; ++k) {
    int idx = srcs[k];
    float2 v = h[(size_t)idx * 64 + lane];
    acc.x += v.x; acc.y += v.y;
  }
  ushort2 o = { f2b(acc.x), f2b(acc.y) };
  *(ushort2*)&A1[(size_t)node * K1 + CIN + lane * 2] = o;
}

// layers 2/3: G from h (Kh=256) -> A23[:, 256:512]
__global__ __launch_bounds__(256) void k_gather256(const float4* __restrict__ h, const int* __restrict__ ptr,
                                                   const int* __restrict__ srcs, ushort* __restrict__ A23) {
  int node = blockIdx.x * 4 + (threadIdx.x >> 6);
  int lane = threadIdx.x & 63;
  float4 acc = h[(size_t)node * 64 + lane];
  int s = ptr[node], e = ptr[node + 1];
  for (int k = s; k < e; ++k) {
    int idx = srcs[k];
    float4 v = h[(size_t)idx * 64 + lane];
    acc.x += v.x; acc.y += v.y; acc.z += v.z; acc.w += v.w;
  }
  ushort4 o = { f2b(acc.x), f2b(acc.y), f2b(acc.z), f2b(acc.w) };
  *(ushort4*)&A23[(size_t)node * K23 + CHID + lane * 4] = o;
}

// ---------------- weight convert/transpose ----------------

// Wt[n][k] = bf16(W[k][n]); n=0..255, k=0..Ktot-1
__global__ __launch_bounds__(256) void k_wt(const float* __restrict__ W, ushort* __restrict__ Wt, int Ktot) {
  int i = blockIdx.x * 256 + threadIdx.x;
  if (i >= 256 * Ktot) return;
  int n = i / Ktot;
  int k = i - n * Ktot;
  Wt[i] = f2b(W[(size_t)k * CHID + n]);
}

// ---------------- MFMA GEMM (M=NN, N=256, K=Ktot) + fused bias/relu/BN-stats ----------------
// out = relu(A @ Wt^T + degf*bias); colsum/colsq += column sums of out
__global__ __launch_bounds__(256) void k_gemm(const ushort* __restrict__ Ag, const ushort* __restrict__ Wt,
                                              const float* __restrict__ bias, const float* __restrict__ degf,
                                              float* __restrict__ out, float* __restrict__ colsum,
                                              float* __restrict__ colsq, int Ktot) {
  __shared__ ushort As[128 * 40];  // 128 rows x 32 k, stride 40 (80B: 16B-aligned, 2-way bank alias = free)
  __shared__ ushort Bs[64 * 40];   // 64 n x 32 k
  const int bm = blockIdx.x * 128;
  const int bn = blockIdx.y * 64;
  const int tid = threadIdx.x;
  const int w = tid >> 6;
  const int lane = tid & 63;
  const int ln = lane & 15;
  const int quad = lane >> 4;

  f4 acc[2][4];
#pragma unroll
  for (int mf = 0; mf < 2; ++mf)
#pragma unroll
    for (int nf = 0; nf < 4; ++nf) acc[mf][nf] = (f4){0.f, 0.f, 0.f, 0.f};

  const int rA = tid >> 1;
  const int hk = (tid & 1) << 4;  // 0 or 16
  const int rowA = bm + rA;
  const int nB = tid >> 2;
  const int kq = (tid & 3) << 3;  // 0,8,16,24

  for (int k0 = 0; k0 < Ktot; k0 += 32) {
    uint4 v0 = {0, 0, 0, 0}, v1 = {0, 0, 0, 0};
    if (rowA < NN) {
      const uint4* p = (const uint4*)(Ag + (size_t)rowA * Ktot + k0 + hk);
      v0 = p[0]; v1 = p[1];
    }
    *(uint4*)&As[rA * 40 + hk] = v0;
    *(uint4*)&As[rA * 40 + hk + 8] = v1;
    uint4 bv = *(const uint4*)(Wt + (size_t)(bn + nB) * Ktot + k0 + kq);
    *(uint4*)&Bs[nB * 40 + kq] = bv;
    __syncthreads();

    sfrag a0 = *(const sfrag*)&As[(w * 32 + ln) * 40 + quad * 8];
    sfrag a1 = *(const sfrag*)&As[(w * 32 + 16 + ln) * 40 + quad * 8];
#pragma unroll
    for (int nf = 0; nf < 4; ++nf) {
      sfrag b = *(const sfrag*)&Bs[(nf * 16 + ln) * 40 + quad * 8];
      acc[0][nf] = __builtin_amdgcn_mfma_f32_16x16x32_bf16(a0, b, acc[0][nf], 0, 0, 0);
      acc[1][nf] = __builtin_amdgcn_mfma_f32_16x16x32_bf16(a1, b, acc[1][nf], 0, 0, 0);
    }
    __syncthreads();
  }

  // epilogue: bias*degf + relu + store + BN partial stats
  float bcol[4];
#pragma unroll
  for (int nf = 0; nf < 4; ++nf) bcol[nf] = bias[bn + nf * 16 + ln];
  float ssum[4] = {0.f, 0.f, 0.f, 0.f}, sqq[4] = {0.f, 0.f, 0.f, 0.f};
#pragma unroll
  for (int mf = 0; mf < 2; ++mf) {
    int rbase = bm + w * 32 + mf * 16 + quad * 4;
#pragma unroll
    for (int r = 0; r < 4; ++r) {
      int row = rbase + r;
      bool valid = row < NN;
      float d = valid ? degf[row] : 0.f;
#pragma unroll
      for (int nf = 0; nf < 4; ++nf) {
        float v = fmaxf(acc[mf][nf][r] + d * bcol[nf], 0.f);
        if (valid) {
          out[(size_t)row * CHID + bn + nf * 16 + ln] = v;
          ssum[nf] += v;
          sqq[nf] += v * v;
        }
      }
    }
  }
#pragma unroll
  for (int nf = 0; nf < 4; ++nf) {
    float s = ssum[nf], q = sqq[nf];
    s += __shfl_xor(s, 16); s += __shfl_xor(s, 32);
    q += __shfl_xor(q, 16); q += __shfl_xor(q, 32);
    if (quad == 0) {
      atomicAdd(&colsum[bn + nf * 16 + ln], s);
      atomicAdd(&colsq[bn + nf * 16 + ln], q);
    }
  }
}

// ---------------- BN finalize + apply ----------------

__global__ __launch_bounds__(256) void k_bnfin(float* __restrict__ colsum, float* __restrict__ colsq,
                                               const float* __restrict__ g, const float* __restrict__ be,
                                               float* __restrict__ scale, float* __restrict__ shift) {
  int c = threadIdx.x;
  float mu = colsum[c] / (float)NN;
  float var = colsq[c] / (float)NN - mu * mu;
  float inv = rsqrtf(var + 1e-5f);
  float sc = g[c] * inv;
  scale[c] = sc;
  shift[c] = be[c] - mu * sc;
  colsum[c] = 0.f;  // ready for next layer
  colsq[c] = 0.f;
}

// in-place: t = relu(t*scale+shift); optionally write bf16(degf*h) panel (next layer A[:,0:256])
__global__ __launch_bounds__(256) void k_bnapply(float4* __restrict__ t, const float* __restrict__ scale,
                                                 const float* __restrict__ shift, ushort* Apanel,
                                                 const float* __restrict__ degf) {
  int gid = blockIdx.x * 256 + threadIdx.x;  // NN*64
  if (gid >= NN * 64) return;
  int node = gid >> 6;
  int c4 = (gid & 63) << 2;
  float4 v = t[gid];
  v.x = fmaxf(fmaf(v.x, scale[c4 + 0], shift[c4 + 0]), 0.f);
  v.y = fmaxf(fmaf(v.y, scale[c4 + 1], shift[c4 + 1]), 0.f);
  v.z = fmaxf(fmaf(v.z, scale[c4 + 2], shift[c4 + 2]), 0.f);
  v.w = fmaxf(fmaf(v.w, scale[c4 + 3], shift[c4 + 3]), 0.f);
  t[gid] = v;
  if (Apanel) {
    float d = degf[node];
    ushort4 o = { f2b(d * v.x), f2b(d * v.y), f2b(d * v.z), f2b(d * v.w) };
    *(ushort4*)&Apanel[(size_t)node * K23 + c4] = o;
  }
}

// ---------------- pooling + MLP ----------------

__global__ __launch_bounds__(256) void k_pool(const float* __restrict__ h, const int* __restrict__ batch,
                                              float* __restrict__ pooled, float* __restrict__ counts) {
  __shared__ int bsh[64];
  int r0 = blockIdx.x * 64;
  int c = threadIdx.x;
  int rows = min(64, NN - r0);
  if (c < rows) bsh[c] = batch[r0 + c];
  __syncthreads();
  float acc = 0.f;
  int cur = bsh[0];
  for (int r = 0; r < rows; ++r) {
    int g = bsh[r];
    if (g != cur) {
      atomicAdd(&pooled[cur * CHID + c], acc);
      acc = 0.f;
      cur = g;
    }
    acc += h[(size_t)(r0 + r) * CHID + c];
  }
  atomicAdd(&pooled[cur * CHID + c], acc);
  if (c == 0) {
    int cur2 = bsh[0], cnt = 0;
    for (int r = 0; r < rows; ++r) {
      if (bsh[r] != cur2) {
        atomicAdd(&counts[cur2], (float)cnt);
        cur2 = bsh[r]; cnt = 0;
      }
      cnt++;
    }
    atomicAdd(&counts[cur2], (float)cnt);
  }
}

__global__ __launch_bounds__(512) void k_mlp(const float* __restrict__ pooled, const float* __restrict__ counts,
                                             const float* __restrict__ nb, const float* __restrict__ w1,
                                             const float* __restrict__ b1, const float* __restrict__ w2,
                                             const float* __restrict__ b2, float* __restrict__ out) {
  int g = blockIdx.x;
  int t = threadIdx.x;
  __shared__ float zin[CHID + 1 + CIN];  // 385
  __shared__ float red[512];
  if (t < CHID) zin[t] = pooled[g * CHID + t];
  else if (t == CHID) zin[CHID] = counts[g] * 0.025f;  // / MAX_SIZE(40)
  else if (t < CHID + 1 + CIN) zin[t] = nb[g * CIN + (t - CHID - 1)];
  __syncthreads();
  float acc = b1[t];
  for (int k = 0; k < CHID + 1 + CIN; ++k) acc = fmaf(zin[k], w1[k * CMLP + t], acc);
  float z = fmaxf(acc, 0.f);
#pragma unroll
  for (int n = 0; n < CNC; ++n) {
    red[t] = z * w2[t * CNC + n];
    __syncthreads();
    for (int s = 256; s > 0; s >>= 1) {
      if (t < s) red[t] += red[t + s];
      __syncthreads();
    }
    if (t == 0) out[g * CNC + n] = red[0] + b2[n];
    __syncthreads();
  }
}

// ---------------- launch ----------------

extern "C" void kernel_launch(void* const* d_in, const int* in_sizes, int n_in,
                              void* d_out, int out_size, void* d_ws, size_t ws_size,
                              hipStream_t stream) {
  const float* x     = (const float*)d_in[0];
  const int*   ei    = (const int*)d_in[1];
  const float* eattr = (const float*)d_in[2];
  const int*   batch = (const int*)d_in[3];
  const float* nbr   = (const float*)d_in[4];
  const float* W1 = (const float*)d_in[5];
  const float* b1 = (const float*)d_in[6];
  const float* g1 = (const float*)d_in[7];
  const float* be1 = (const float*)d_in[8];
  const float* W2 = (const float*)d_in[9];
  const float* b2 = (const float*)d_in[10];
  const float* g2 = (const float*)d_in[11];
  const float* be2 = (const float*)d_in[12];
  const float* W3 = (const float*)d_in[13];
  const float* b3 = (const float*)d_in[14];
  const float* g3 = (const float*)d_in[15];
  const float* be3 = (const float*)d_in[16];
  const float* fc1w = (const float*)d_in[17];
  const float* fc1b = (const float*)d_in[18];
  const float* fc2w = (const float*)d_in[19];
  const float* fc2b = (const float*)d_in[20];
  float* out = (float*)d_out;

  char* ws = (char*)d_ws;
  size_t off = 0;
  auto alloc = [&](size_t bytes) {
    void* p = ws + off;
    off = (off + bytes + 255) & ~(size_t)255;
    return p;
  };
  int*    ptr    = (int*)alloc((NN + 1) * sizeof(int));
  int*    pos    = (int*)alloc(NN * sizeof(int));
  float*  degf   = (float*)alloc(NN * sizeof(float));
  int*    eid    = (int*)alloc(NE * sizeof(int));
  int*    srcs   = (int*)alloc(NE * sizeof(int));
  ushort* A1     = (ushort*)alloc((size_t)NN * K1 * sizeof(ushort));
  ushort* A23    = (ushort*)alloc((size_t)NN * K23 * sizeof(ushort));
  ushort* Wt1    = (ushort*)alloc((size_t)256 * K1 * sizeof(ushort));
  ushort* Wt2    = (ushort*)alloc((size_t)256 * K23 * sizeof(ushort));
  ushort* Wt3    = (ushort*)alloc((size_t)256 * K23 * sizeof(ushort));
  float*  tmp    = (float*)alloc((size_t)NN * CHID * sizeof(float));  // doubles as h (in-place BN)
  float*  colsum = (float*)alloc(CHID * sizeof(float));
  float*  colsq  = (float*)alloc(CHID * sizeof(float));
  float*  scale  = (float*)alloc(CHID * sizeof(float));
  float*  shift  = (float*)alloc(CHID * sizeof(float));
  float*  pooled = (float*)alloc((size_t)NB * CHID * sizeof(float));
  float*  counts = (float*)alloc(NB * sizeof(float));
  (void)ws_size; (void)n_in; (void)in_sizes; (void)out_size;

  // CSR + static aggregates
  k_init<<<cdiv(NB * CHID, 256), 256, 0, stream>>>(ptr, pooled, counts, colsum, colsq);
  k_count<<<cdiv(NE, 256), 256, 0, stream>>>(ei, ptr);
  k_scan<<<1, 1024, 0, stream>>>(ptr);
  k_degpos<<<cdiv(NN, 256), 256, 0, stream>>>(ptr, pos, degf);
  k_fill<<<cdiv(NE, 256), 256, 0, stream>>>(ei, pos, eid, srcs);
  k_ea<<<NN / 4, 256, 0, stream>>>(eattr, ptr, eid, A1, A23);
  k_wt<<<cdiv(256 * K1, 256), 256, 0, stream>>>(W1, Wt1, K1);
  k_wt<<<cdiv(256 * K23, 256), 256, 0, stream>>>(W2, Wt2, K23);
  k_wt<<<cdiv(256 * K23, 256), 256, 0, stream>>>(W3, Wt3, K23);
  k_prep<<<cdiv(NN * (CIN / 4), 256), 256, 0, stream>>>((const float4*)x, degf, A1);

  dim3 ggrid(cdiv(NN, 128), CHID / 64);

  // layer 1
  k_gather128<<<NN / 4, 256, 0, stream>>>((const float2*)x, ptr, srcs, A1);
  k_gemm<<<ggrid, 256, 0, stream>>>(A1, Wt1, b1, degf, tmp, colsum, colsq, K1);
  k_bnfin<<<1, 256, 0, stream>>>(colsum, colsq, g1, be1, scale, shift);
  k_bnapply<<<cdiv(NN * 64, 256), 256, 0, stream>>>((float4*)tmp, scale, shift, A23, degf);

  // layer 2
  k_gather256<<<NN / 4, 256, 0, stream>>>((const float4*)tmp, ptr, srcs, A23);
  k_gemm<<<ggrid, 256, 0, stream>>>(A23, Wt2, b2, degf, tmp, colsum, colsq, K23);
  k_bnfin<<<1, 256, 0, stream>>>(colsum, colsq, g2, be2, scale, shift);
  k_bnapply<<<cdiv(NN * 64, 256), 256, 0, stream>>>((float4*)tmp, scale, shift, A23, degf);

  // layer 3
  k_gather256<<<NN / 4, 256, 0, stream>>>((const float4*)tmp, ptr, srcs, A23);
  k_gemm<<<ggrid, 256, 0, stream>>>(A23, Wt3, b3, degf, tmp, colsum, colsq, K23);
  k_bnfin<<<1, 256, 0, stream>>>(colsum, colsq, g3, be3, scale, shift);
  k_bnapply<<<cdiv(NN * 64, 256), 256, 0, stream>>>((float4*)tmp, scale, shift, (ushort*)nullptr, degf);

  // pool + MLP head
  k_pool<<<cdiv(NN, 64), 256, 0, stream>>>(tmp, batch, pooled, counts);
  k_mlp<<<NB, 512, 0, stream>>>(pooled, counts, nbr, fc1w, fc1b, fc2w, fc2b, out);
}

// Round 3
// 447.313 us; speedup vs baseline: 1.3323x; 1.2638x over previous
//
#include <hip/hip_runtime.h>

#define NN 10000      // nodes
#define NE 320000     // edges (before self-loops)
#define NB 64         // graphs
#define CIN 128       // in_channels
#define CEC 64        // edge_channels
#define CHID 256      // hidden
#define CMLP 512
#define CNC 4
#define K1 (2 * CIN + CEC)    // 320
#define K23 (2 * CHID + CEC)  // 576

static __host__ int cdiv(int a, int b) { return (a + b - 1) / b; }

typedef short sfrag __attribute__((ext_vector_type(8)));   // 8 bf16 in 4 VGPRs
typedef float f4 __attribute__((ext_vector_type(4)));

static __device__ __forceinline__ ushort f2b(float f) {
  union { float f; unsigned u; } v; v.f = f;
  unsigned r = (v.u + 0x7fffu + ((v.u >> 16) & 1u)) >> 16;
  return (ushort)r;
}
static __device__ __forceinline__ float b2f(ushort u) {
  union { unsigned u; float f; } v; v.u = ((unsigned)u) << 16;
  return v.f;
}

// ---------------- setup kernels ----------------

__global__ __launch_bounds__(256) void k_init(int* __restrict__ ptr, float* __restrict__ pooled,
                                              float* __restrict__ counts, float* __restrict__ colsum,
                                              float* __restrict__ colsq) {
  int i = blockIdx.x * 256 + threadIdx.x;
  if (i <= NN) ptr[i] = 0;
  if (i < NB * CHID) pooled[i] = 0.f;
  if (i < NB) counts[i] = 0.f;
  if (i < CHID) { colsum[i] = 0.f; colsq[i] = 0.f; }
}

__global__ __launch_bounds__(256) void k_count(const int* __restrict__ ei, int* __restrict__ ptr) {
  int e = blockIdx.x * 256 + threadIdx.x;
  if (e < NE) atomicAdd(&ptr[ei[NE + e] + 1], 1);
}

// single-block inclusive scan over ptr[0..NN], shfl-based (3 barriers/chunk)
__global__ __launch_bounds__(1024) void k_scan(int* __restrict__ ptr) {
  __shared__ int wsum[16];
  __shared__ int chtot;
  int carry = 0;
  const int n1 = NN + 1;
  const int lane = threadIdx.x & 63;
  const int wid = threadIdx.x >> 6;
  for (int base = 0; base < n1; base += 1024) {
    int i = base + threadIdx.x;
    int v = (i < n1) ? ptr[i] : 0;
    int sc = v;
#pragma unroll
    for (int d = 1; d < 64; d <<= 1) {
      int t = __shfl_up(sc, d);
      if (lane >= d) sc += t;
    }
    if (lane == 63) wsum[wid] = sc;
    __syncthreads();
    if (wid == 0 && lane < 16) {
      int ws = wsum[lane];
      int s2 = ws;
#pragma unroll
      for (int d = 1; d < 16; d <<= 1) {
        int t = __shfl_up(s2, d);
        if (lane >= d) s2 += t;
      }
      wsum[lane] = s2 - ws;  // exclusive
      if (lane == 15) chtot = s2;
    }
    __syncthreads();
    if (i < n1) ptr[i] = sc + wsum[wid] + carry;
    carry += chtot;
    __syncthreads();
  }
}

__global__ __launch_bounds__(256) void k_degpos(const int* __restrict__ ptr, int* __restrict__ pos,
                                                float* __restrict__ degf) {
  int i = blockIdx.x * 256 + threadIdx.x;
  if (i < NN) {
    pos[i] = ptr[i];
    degf[i] = (float)(ptr[i + 1] - ptr[i] + 1);  // +1 self-loop
  }
}

__global__ __launch_bounds__(256) void k_fill(const int* __restrict__ ei, int* __restrict__ pos,
                                              int* __restrict__ eid, int* __restrict__ srcs) {
  int e = blockIdx.x * 256 + threadIdx.x;
  if (e < NE) {
    int d = ei[NE + e];
    int idx = atomicAdd(&pos[d], 1);
    eid[idx] = e;
    srcs[idx] = ei[e];
  }
}

// ea_sum[i][c] = 1 + sum of incoming edge_attr; bf16 into both A panels
// wave per node; 16-index shfl-broadcast chunks for MLP
__global__ __launch_bounds__(256) void k_ea(const float* __restrict__ eattr, const int* __restrict__ ptr,
                                            const int* __restrict__ eid, ushort* __restrict__ A1,
                                            ushort* __restrict__ A23) {
  int node = blockIdx.x * 4 + (threadIdx.x >> 6);
  int lane = threadIdx.x & 63;
  int s = ptr[node], e = ptr[node + 1];
  float acc = 1.0f;  // PyG self-loop edge_attr fill
  for (int k0 = s; k0 < e; k0 += 16) {
    int rem = e - k0;
    int myi = (lane < 16 && lane < rem) ? eid[k0 + lane] : 0;
    if (rem >= 16) {
#pragma unroll
      for (int j = 0; j < 16; ++j) {
        int idx = __shfl(myi, j);
        acc += eattr[(size_t)idx * CEC + lane];
      }
    } else {
#pragma unroll
      for (int j = 0; j < 16; ++j) {
        int idx = __shfl(myi, j);
        float v = eattr[(size_t)idx * CEC + lane];
        if (j < rem) acc += v;
      }
    }
  }
  ushort b = f2b(acc);
  A1[(size_t)node * K1 + 2 * CIN + lane] = b;
  A23[(size_t)node * K23 + 2 * CHID + lane] = b;
}

// A1[:, 0:128] = bf16(degf * x); xb = bf16(x)
__global__ __launch_bounds__(256) void k_prep(const float4* __restrict__ x, const float* __restrict__ degf,
                                              ushort* __restrict__ A1, ushort* __restrict__ xb) {
  int gid = blockIdx.x * 256 + threadIdx.x;  // NN*32
  if (gid >= NN * (CIN / 4)) return;
  int node = gid >> 5;
  int c4 = (gid & 31) << 2;
  float d = degf[node];
  float4 v = x[gid];
  ushort4 o = { f2b(d * v.x), f2b(d * v.y), f2b(d * v.z), f2b(d * v.w) };
  *(ushort4*)&A1[(size_t)node * K1 + c4] = o;
  ushort4 xo = { f2b(v.x), f2b(v.y), f2b(v.z), f2b(v.w) };
  *(ushort4*)&xb[(size_t)node * CIN + c4] = xo;
}

// ---------------- gathers (wave per node, shfl-broadcast, bf16 input) ----------------

// layer 1: G from xb (Kh=128) -> A1[:, 128:256]
__global__ __launch_bounds__(256) void k_gather128(const ushort* __restrict__ xb, const int* __restrict__ ptr,
                                                   const int* __restrict__ srcs, ushort* __restrict__ A1) {
  int node = blockIdx.x * 4 + (threadIdx.x >> 6);
  int lane = threadIdx.x & 63;
  ushort2 own = *(const ushort2*)&xb[(size_t)node * CIN + lane * 2];
  float ax = b2f(own.x), ay = b2f(own.y);
  int s = ptr[node], e = ptr[node + 1];
  for (int k0 = s; k0 < e; k0 += 16) {
    int rem = e - k0;
    int myi = (lane < 16 && lane < rem) ? srcs[k0 + lane] : 0;
    if (rem >= 16) {
#pragma unroll
      for (int j = 0; j < 16; ++j) {
        int idx = __shfl(myi, j);
        ushort2 v = *(const ushort2*)&xb[(size_t)idx * CIN + lane * 2];
        ax += b2f(v.x); ay += b2f(v.y);
      }
    } else {
#pragma unroll
      for (int j = 0; j < 16; ++j) {
        int idx = __shfl(myi, j);
        ushort2 v = *(const ushort2*)&xb[(size_t)idx * CIN + lane * 2];
        if (j < rem) { ax += b2f(v.x); ay += b2f(v.y); }
      }
    }
  }
  ushort2 o = { f2b(ax), f2b(ay) };
  *(ushort2*)&A1[(size_t)node * K1 + CIN + lane * 2] = o;
}

// layers 2/3: G from hb (Kh=256) -> A23[:, 256:512]
__global__ __launch_bounds__(256) void k_gather256(const ushort* __restrict__ hb, const int* __restrict__ ptr,
                                                   const int* __restrict__ srcs, ushort* __restrict__ A23) {
  int node = blockIdx.x * 4 + (threadIdx.x >> 6);
  int lane = threadIdx.x & 63;
  ushort4 own = *(const ushort4*)&hb[(size_t)node * CHID + lane * 4];
  float ax = b2f(own.x), ay = b2f(own.y), az = b2f(own.z), aw = b2f(own.w);
  int s = ptr[node], e = ptr[node + 1];
  for (int k0 = s; k0 < e; k0 += 16) {
    int rem = e - k0;
    int myi = (lane < 16 && lane < rem) ? srcs[k0 + lane] : 0;
    if (rem >= 16) {
#pragma unroll
      for (int j = 0; j < 16; ++j) {
        int idx = __shfl(myi, j);
        ushort4 v = *(const ushort4*)&hb[(size_t)idx * CHID + lane * 4];
        ax += b2f(v.x); ay += b2f(v.y); az += b2f(v.z); aw += b2f(v.w);
      }
    } else {
#pragma unroll
      for (int j = 0; j < 16; ++j) {
        int idx = __shfl(myi, j);
        ushort4 v = *(const ushort4*)&hb[(size_t)idx * CHID + lane * 4];
        if (j < rem) { ax += b2f(v.x); ay += b2f(v.y); az += b2f(v.z); aw += b2f(v.w); }
      }
    }
  }
  ushort4 o = { f2b(ax), f2b(ay), f2b(az), f2b(aw) };
  *(ushort4*)&A23[(size_t)node * K23 + CHID + lane * 4] = o;
}

// ---------------- weight convert/transpose ----------------

// Wt[n][k] = bf16(W[k][n]); n=0..255, k=0..Ktot-1
__global__ __launch_bounds__(256) void k_wt(const float* __restrict__ W, ushort* __restrict__ Wt, int Ktot) {
  int i = blockIdx.x * 256 + threadIdx.x;
  if (i >= 256 * Ktot) return;
  int n = i / Ktot;
  int k = i - n * Ktot;
  Wt[i] = f2b(W[(size_t)k * CHID + n]);
}

// ---------------- MFMA GEMM (M=NN, N=256, K=Ktot) + fused bias/relu/BN-stats ----------------
__global__ __launch_bounds__(256) void k_gemm(const ushort* __restrict__ Ag, const ushort* __restrict__ Wt,
                                              const float* __restrict__ bias, const float* __restrict__ degf,
                                              float* __restrict__ out, float* __restrict__ colsum,
                                              float* __restrict__ colsq, int Ktot) {
  __shared__ ushort As[128 * 40];  // 128 rows x 32 k, stride 40
  __shared__ ushort Bs[64 * 40];   // 64 n x 32 k
  const int bm = blockIdx.x * 128;
  const int bn = blockIdx.y * 64;
  const int tid = threadIdx.x;
  const int w = tid >> 6;
  const int lane = tid & 63;
  const int ln = lane & 15;
  const int quad = lane >> 4;

  f4 acc[2][4];
#pragma unroll
  for (int mf = 0; mf < 2; ++mf)
#pragma unroll
    for (int nf = 0; nf < 4; ++nf) acc[mf][nf] = (f4){0.f, 0.f, 0.f, 0.f};

  const int rA = tid >> 1;
  const int hk = (tid & 1) << 4;  // 0 or 16
  const int rowA = bm + rA;
  const int nB = tid >> 2;
  const int kq = (tid & 3) << 3;  // 0,8,16,24

  for (int k0 = 0; k0 < Ktot; k0 += 32) {
    uint4 v0 = {0, 0, 0, 0}, v1 = {0, 0, 0, 0};
    if (rowA < NN) {
      const uint4* p = (const uint4*)(Ag + (size_t)rowA * Ktot + k0 + hk);
      v0 = p[0]; v1 = p[1];
    }
    *(uint4*)&As[rA * 40 + hk] = v0;
    *(uint4*)&As[rA * 40 + hk + 8] = v1;
    uint4 bv = *(const uint4*)(Wt + (size_t)(bn + nB) * Ktot + k0 + kq);
    *(uint4*)&Bs[nB * 40 + kq] = bv;
    __syncthreads();

    sfrag a0 = *(const sfrag*)&As[(w * 32 + ln) * 40 + quad * 8];
    sfrag a1 = *(const sfrag*)&As[(w * 32 + 16 + ln) * 40 + quad * 8];
#pragma unroll
    for (int nf = 0; nf < 4; ++nf) {
      sfrag b = *(const sfrag*)&Bs[(nf * 16 + ln) * 40 + quad * 8];
      acc[0][nf] = __builtin_amdgcn_mfma_f32_16x16x32_bf16(a0, b, acc[0][nf], 0, 0, 0);
      acc[1][nf] = __builtin_amdgcn_mfma_f32_16x16x32_bf16(a1, b, acc[1][nf], 0, 0, 0);
    }
    __syncthreads();
  }

  float bcol[4];
#pragma unroll
  for (int nf = 0; nf < 4; ++nf) bcol[nf] = bias[bn + nf * 16 + ln];
  float ssum[4] = {0.f, 0.f, 0.f, 0.f}, sqq[4] = {0.f, 0.f, 0.f, 0.f};
#pragma unroll
  for (int mf = 0; mf < 2; ++mf) {
    int rbase = bm + w * 32 + mf * 16 + quad * 4;
#pragma unroll
    for (int r = 0; r < 4; ++r) {
      int row = rbase + r;
      bool valid = row < NN;
      float d = valid ? degf[row] : 0.f;
#pragma unroll
      for (int nf = 0; nf < 4; ++nf) {
        float v = fmaxf(acc[mf][nf][r] + d * bcol[nf], 0.f);
        if (valid) {
          out[(size_t)row * CHID + bn + nf * 16 + ln] = v;
          ssum[nf] += v;
          sqq[nf] += v * v;
        }
      }
    }
  }
#pragma unroll
  for (int nf = 0; nf < 4; ++nf) {
    float s = ssum[nf], q = sqq[nf];
    s += __shfl_xor(s, 16); s += __shfl_xor(s, 32);
    q += __shfl_xor(q, 16); q += __shfl_xor(q, 32);
    if (quad == 0) {
      atomicAdd(&colsum[bn + nf * 16 + ln], s);
      atomicAdd(&colsq[bn + nf * 16 + ln], q);
    }
  }
}

// ---------------- BN finalize + apply ----------------

__global__ __launch_bounds__(256) void k_bnfin(float* __restrict__ colsum, float* __restrict__ colsq,
                                               const float* __restrict__ g, const float* __restrict__ be,
                                               float* __restrict__ scale, float* __restrict__ shift) {
  int c = threadIdx.x;
  float mu = colsum[c] / (float)NN;
  float var = colsq[c] / (float)NN - mu * mu;
  float inv = rsqrtf(var + 1e-5f);
  float sc = g[c] * inv;
  scale[c] = sc;
  shift[c] = be[c] - mu * sc;
  colsum[c] = 0.f;  // ready for next layer
  colsq[c] = 0.f;
}

// in-place: t = relu(t*scale+shift); writes bf16 shadow hb; optionally bf16(degf*h) A-panel
__global__ __launch_bounds__(256) void k_bnapply(float4* __restrict__ t, const float* __restrict__ scale,
                                                 const float* __restrict__ shift, ushort* Apanel,
                                                 ushort* __restrict__ hb, const float* __restrict__ degf) {
  int gid = blockIdx.x * 256 + threadIdx.x;  // NN*64
  if (gid >= NN * 64) return;
  int node = gid >> 6;
  int c4 = (gid & 63) << 2;
  float4 v = t[gid];
  v.x = fmaxf(fmaf(v.x, scale[c4 + 0], shift[c4 + 0]), 0.f);
  v.y = fmaxf(fmaf(v.y, scale[c4 + 1], shift[c4 + 1]), 0.f);
  v.z = fmaxf(fmaf(v.z, scale[c4 + 2], shift[c4 + 2]), 0.f);
  v.w = fmaxf(fmaf(v.w, scale[c4 + 3], shift[c4 + 3]), 0.f);
  t[gid] = v;
  ushort4 ho = { f2b(v.x), f2b(v.y), f2b(v.z), f2b(v.w) };
  *(ushort4*)&hb[(size_t)node * CHID + c4] = ho;
  if (Apanel) {
    float d = degf[node];
    ushort4 o = { f2b(d * v.x), f2b(d * v.y), f2b(d * v.z), f2b(d * v.w) };
    *(ushort4*)&Apanel[(size_t)node * K23 + c4] = o;
  }
}

// ---------------- pooling + MLP ----------------

__global__ __launch_bounds__(256) void k_pool(const float* __restrict__ h, const int* __restrict__ batch,
                                              float* __restrict__ pooled, float* __restrict__ counts) {
  __shared__ int bsh[64];
  int r0 = blockIdx.x * 64;
  int c = threadIdx.x;
  int rows = min(64, NN - r0);
  if (c < rows) bsh[c] = batch[r0 + c];
  __syncthreads();
  float acc = 0.f;
  int cur = bsh[0];
  for (int r = 0; r < rows; ++r) {
    int g = bsh[r];
    if (g != cur) {
      atomicAdd(&pooled[cur * CHID + c], acc);
      acc = 0.f;
      cur = g;
    }
    acc += h[(size_t)(r0 + r) * CHID + c];
  }
  atomicAdd(&pooled[cur * CHID + c], acc);
  if (c == 0) {
    int cur2 = bsh[0], cnt = 0;
    for (int r = 0; r < rows; ++r) {
      if (bsh[r] != cur2) {
        atomicAdd(&counts[cur2], (float)cnt);
        cur2 = bsh[r]; cnt = 0;
      }
      cnt++;
    }
    atomicAdd(&counts[cur2], (float)cnt);
  }
}

__global__ __launch_bounds__(512) void k_mlp(const float* __restrict__ pooled, const float* __restrict__ counts,
                                             const float* __restrict__ nb, const float* __restrict__ w1,
                                             const float* __restrict__ b1, const float* __restrict__ w2,
                                             const float* __restrict__ b2, float* __restrict__ out) {
  int g = blockIdx.x;
  int t = threadIdx.x;
  __shared__ float zin[CHID + 1 + CIN];  // 385
  __shared__ float red[512];
  if (t < CHID) zin[t] = pooled[g * CHID + t];
  else if (t == CHID) zin[CHID] = counts[g] * 0.025f;  // / MAX_SIZE(40)
  else if (t < CHID + 1 + CIN) zin[t] = nb[g * CIN + (t - CHID - 1)];
  __syncthreads();
  float acc = b1[t];
  for (int k = 0; k < CHID + 1 + CIN; ++k) acc = fmaf(zin[k], w1[k * CMLP + t], acc);
  float z = fmaxf(acc, 0.f);
#pragma unroll
  for (int n = 0; n < CNC; ++n) {
    red[t] = z * w2[t * CNC + n];
    __syncthreads();
    for (int s = 256; s > 0; s >>= 1) {
      if (t < s) red[t] += red[t + s];
      __syncthreads();
    }
    if (t == 0) out[g * CNC + n] = red[0] + b2[n];
    __syncthreads();
  }
}

// ---------------- launch ----------------

extern "C" void kernel_launch(void* const* d_in, const int* in_sizes, int n_in,
                              void* d_out, int out_size, void* d_ws, size_t ws_size,
                              hipStream_t stream) {
  const float* x     = (const float*)d_in[0];
  const int*   ei    = (const int*)d_in[1];
  const float* eattr = (const float*)d_in[2];
  const int*   batch = (const int*)d_in[3];
  const float* nbr   = (const float*)d_in[4];
  const float* W1 = (const float*)d_in[5];
  const float* b1 = (const float*)d_in[6];
  const float* g1 = (const float*)d_in[7];
  const float* be1 = (const float*)d_in[8];
  const float* W2 = (const float*)d_in[9];
  const float* b2 = (const float*)d_in[10];
  const float* g2 = (const float*)d_in[11];
  const float* be2 = (const float*)d_in[12];
  const float* W3 = (const float*)d_in[13];
  const float* b3 = (const float*)d_in[14];
  const float* g3 = (const float*)d_in[15];
  const float* be3 = (const float*)d_in[16];
  const float* fc1w = (const float*)d_in[17];
  const float* fc1b = (const float*)d_in[18];
  const float* fc2w = (const float*)d_in[19];
  const float* fc2b = (const float*)d_in[20];
  float* out = (float*)d_out;

  char* ws = (char*)d_ws;
  size_t off = 0;
  auto alloc = [&](size_t bytes) {
    void* p = ws + off;
    off = (off + bytes + 255) & ~(size_t)255;
    return p;
  };
  int*    ptr    = (int*)alloc((NN + 1) * sizeof(int));
  int*    pos    = (int*)alloc(NN * sizeof(int));
  float*  degf   = (float*)alloc(NN * sizeof(float));
  int*    eid    = (int*)alloc(NE * sizeof(int));
  int*    srcs   = (int*)alloc(NE * sizeof(int));
  ushort* A1     = (ushort*)alloc((size_t)NN * K1 * sizeof(ushort));
  ushort* A23    = (ushort*)alloc((size_t)NN * K23 * sizeof(ushort));
  ushort* Wt1    = (ushort*)alloc((size_t)256 * K1 * sizeof(ushort));
  ushort* Wt2    = (ushort*)alloc((size_t)256 * K23 * sizeof(ushort));
  ushort* Wt3    = (ushort*)alloc((size_t)256 * K23 * sizeof(ushort));
  ushort* xb     = (ushort*)alloc((size_t)NN * CIN * sizeof(ushort));
  ushort* hb     = (ushort*)alloc((size_t)NN * CHID * sizeof(ushort));
  float*  tmp    = (float*)alloc((size_t)NN * CHID * sizeof(float));  // in-place BN
  float*  colsum = (float*)alloc(CHID * sizeof(float));
  float*  colsq  = (float*)alloc(CHID * sizeof(float));
  float*  scale  = (float*)alloc(CHID * sizeof(float));
  float*  shift  = (float*)alloc(CHID * sizeof(float));
  float*  pooled = (float*)alloc((size_t)NB * CHID * sizeof(float));
  float*  counts = (float*)alloc(NB * sizeof(float));
  (void)ws_size; (void)n_in; (void)in_sizes; (void)out_size;

  // CSR + static aggregates
  k_init<<<cdiv(NB * CHID, 256), 256, 0, stream>>>(ptr, pooled, counts, colsum, colsq);
  k_count<<<cdiv(NE, 256), 256, 0, stream>>>(ei, ptr);
  k_scan<<<1, 1024, 0, stream>>>(ptr);
  k_degpos<<<cdiv(NN, 256), 256, 0, stream>>>(ptr, pos, degf);
  k_fill<<<cdiv(NE, 256), 256, 0, stream>>>(ei, pos, eid, srcs);
  k_ea<<<NN / 4, 256, 0, stream>>>(eattr, ptr, eid, A1, A23);
  k_wt<<<cdiv(256 * K1, 256), 256, 0, stream>>>(W1, Wt1, K1);
  k_wt<<<cdiv(256 * K23, 256), 256, 0, stream>>>(W2, Wt2, K23);
  k_wt<<<cdiv(256 * K23, 256), 256, 0, stream>>>(W3, Wt3, K23);
  k_prep<<<cdiv(NN * (CIN / 4), 256), 256, 0, stream>>>((const float4*)x, degf, A1, xb);

  dim3 ggrid(cdiv(NN, 128), CHID / 64);

  // layer 1
  k_gather128<<<NN / 4, 256, 0, stream>>>(xb, ptr, srcs, A1);
  k_gemm<<<ggrid, 256, 0, stream>>>(A1, Wt1, b1, degf, tmp, colsum, colsq, K1);
  k_bnfin<<<1, 256, 0, stream>>>(colsum, colsq, g1, be1, scale, shift);
  k_bnapply<<<cdiv(NN * 64, 256), 256, 0, stream>>>((float4*)tmp, scale, shift, A23, hb, degf);

  // layer 2
  k_gather256<<<NN / 4, 256, 0, stream>>>(hb, ptr, srcs, A23);
  k_gemm<<<ggrid, 256, 0, stream>>>(A23, Wt2, b2, degf, tmp, colsum, colsq, K23);
  k_bnfin<<<1, 256, 0, stream>>>(colsum, colsq, g2, be2, scale, shift);
  k_bnapply<<<cdiv(NN * 64, 256), 256, 0, stream>>>((float4*)tmp, scale, shift, A23, hb, degf);

  // layer 3
  k_gather256<<<NN / 4, 256, 0, stream>>>(hb, ptr, srcs, A23);
  k_gemm<<<ggrid, 256, 0, stream>>>(A23, Wt3, b3, degf, tmp, colsum, colsq, K23);
  k_bnfin<<<1, 256, 0, stream>>>(colsum, colsq, g3, be3, scale, shift);
  k_bnapply<<<cdiv(NN * 64, 256), 256, 0, stream>>>((float4*)tmp, scale, shift, (ushort*)nullptr, hb, degf);

  // pool + MLP head
  k_pool<<<cdiv(NN, 64), 256, 0, stream>>>(tmp, batch, pooled, counts);
  k_mlp<<<NB, 512, 0, stream>>>(pooled, counts, nbr, fc1w, fc1b, fc2w, fc2b, out);
}

// Round 4
// 442.414 us; speedup vs baseline: 1.3470x; 1.0111x over previous
//
#include <hip/hip_runtime.h>

#define NN 10000      // nodes
#define NE 320000     // edges (before self-loops)
#define NB 64         // graphs
#define CIN 128       // in_channels
#define CEC 64        // edge_channels
#define CHID 256      // hidden
#define CMLP 512
#define CNC 4
#define K1 (2 * CIN + CEC)    // 320
#define K23 (2 * CHID + CEC)  // 576

static __host__ int cdiv(int a, int b) { return (a + b - 1) / b; }

typedef short sfrag __attribute__((ext_vector_type(8)));   // 8 bf16 in 4 VGPRs
typedef float f4 __attribute__((ext_vector_type(4)));

static __device__ __forceinline__ ushort f2b(float f) {
  union { float f; unsigned u; } v; v.f = f;
  unsigned r = (v.u + 0x7fffu + ((v.u >> 16) & 1u)) >> 16;
  return (ushort)r;
}
static __device__ __forceinline__ float b2f(ushort u) {
  union { unsigned u; float f; } v; v.u = ((unsigned)u) << 16;
  return v.f;
}

// ---------------- setup kernels ----------------

// zero ptr, pooled, counts, per-layer BN stat buffers (stats = 6*CHID floats)
__global__ __launch_bounds__(256) void k_init(int* __restrict__ ptr, float* __restrict__ pooled,
                                              float* __restrict__ counts, float* __restrict__ stats) {
  int i = blockIdx.x * 256 + threadIdx.x;
  if (i <= NN) ptr[i] = 0;
  if (i < NB * CHID) pooled[i] = 0.f;
  if (i < NB) counts[i] = 0.f;
  if (i < 6 * CHID) stats[i] = 0.f;
}

// blocks [0,1250): edge-degree histogram; blocks [1250,1290): batch histogram -> counts
__global__ __launch_bounds__(256) void k_count(const int* __restrict__ ei, int* __restrict__ ptr,
                                               const int* __restrict__ batch, float* __restrict__ counts) {
  int b = blockIdx.x;
  if (b < 1250) {
    int e = b * 256 + threadIdx.x;  // 1250*256 == NE exactly
    atomicAdd(&ptr[ei[NE + e] + 1], 1);
  } else {
    __shared__ int hist[NB];
    if (threadIdx.x < NB) hist[threadIdx.x] = 0;
    __syncthreads();
    int n = (b - 1250) * 256 + threadIdx.x;
    if (n < NN) atomicAdd(&hist[batch[n]], 1);
    __syncthreads();
    if (threadIdx.x < NB && hist[threadIdx.x]) atomicAdd(&counts[threadIdx.x], (float)hist[threadIdx.x]);
  }
}

// single-block inclusive scan over ptr[0..NN] + fused pos/degf writeout
__global__ __launch_bounds__(1024) void k_scan(int* __restrict__ ptr, int* __restrict__ pos,
                                               float* __restrict__ degf) {
  __shared__ int wsum[16];
  __shared__ int chtot;
  int carry = 0;
  const int n1 = NN + 1;
  const int lane = threadIdx.x & 63;
  const int wid = threadIdx.x >> 6;
  for (int base = 0; base < n1; base += 1024) {
    int i = base + threadIdx.x;
    int v = (i < n1) ? ptr[i] : 0;
    int sc = v;
#pragma unroll
    for (int d = 1; d < 64; d <<= 1) {
      int t = __shfl_up(sc, d);
      if (lane >= d) sc += t;
    }
    if (lane == 63) wsum[wid] = sc;
    __syncthreads();
    if (wid == 0 && lane < 16) {
      int ws = wsum[lane];
      int s2 = ws;
#pragma unroll
      for (int d = 1; d < 16; d <<= 1) {
        int t = __shfl_up(s2, d);
        if (lane >= d) s2 += t;
      }
      wsum[lane] = s2 - ws;  // exclusive
      if (lane == 15) chtot = s2;
    }
    __syncthreads();
    if (i < n1) ptr[i] = sc + wsum[wid] + carry;
    carry += chtot;
    __syncthreads();
  }
  // fused degpos (all ptr writes complete; same block)
  for (int i = threadIdx.x; i < NN; i += 1024) {
    int p = ptr[i], q = ptr[i + 1];
    pos[i] = p;
    degf[i] = (float)(q - p + 1);  // +1 self-loop
  }
}

__global__ __launch_bounds__(256) void k_fill(const int* __restrict__ ei, int* __restrict__ pos,
                                              int* __restrict__ eid, int* __restrict__ srcs) {
  int e = blockIdx.x * 256 + threadIdx.x;  // 1250*256 == NE
  int d = ei[NE + e];
  int idx = atomicAdd(&pos[d], 1);
  eid[idx] = e;
  srcs[idx] = ei[e];
}

// A1[:, 0:128] = bf16(degf * x); xb = bf16(x)
__global__ __launch_bounds__(256) void k_prep(const float4* __restrict__ x, const float* __restrict__ degf,
                                              ushort* __restrict__ A1, ushort* __restrict__ xb) {
  int gid = blockIdx.x * 256 + threadIdx.x;  // NN*32 = 320000 = 1250*256
  int node = gid >> 5;
  int c4 = (gid & 31) << 2;
  float d = degf[node];
  float4 v = x[gid];
  ushort4 o = { f2b(d * v.x), f2b(d * v.y), f2b(d * v.z), f2b(d * v.w) };
  *(ushort4*)&A1[(size_t)node * K1 + c4] = o;
  ushort4 xo = { f2b(v.x), f2b(v.y), f2b(v.z), f2b(v.w) };
  *(ushort4*)&xb[(size_t)node * CIN + c4] = xo;
}

// fused: ea_sum (both panels) + layer-1 gather of x. Wave per node.
// lanes 0-15 carry eid chunk, lanes 16-31 carry srcs chunk (shared shfl broadcast).
__global__ __launch_bounds__(256) void k_eag(const float* __restrict__ eattr, const ushort* __restrict__ xb,
                                             const int* __restrict__ ptr, const int* __restrict__ eid,
                                             const int* __restrict__ srcs, ushort* __restrict__ A1,
                                             ushort* __restrict__ A23) {
  int node = blockIdx.x * 4 + (threadIdx.x >> 6);
  int lane = threadIdx.x & 63;
  int s = ptr[node], e = ptr[node + 1];
  float ea_acc = 1.0f;  // PyG self-loop edge_attr fill
  ushort2 own = *(const ushort2*)&xb[(size_t)node * CIN + lane * 2];
  float gx = b2f(own.x), gy = b2f(own.y);
  for (int k0 = s; k0 < e; k0 += 16) {
    int rem = e - k0;
    int comb = 0;
    if (lane < 16) { if (lane < rem) comb = eid[k0 + lane]; }
    else if (lane < 32) { if (lane - 16 < rem) comb = srcs[k0 + lane - 16]; }
    if (rem >= 16) {
#pragma unroll
      for (int j = 0; j < 16; ++j) {
        int eidx = __shfl(comb, j);
        int sidx = __shfl(comb, 16 + j);
        ea_acc += eattr[(size_t)eidx * CEC + lane];
        ushort2 v = *(const ushort2*)&xb[(size_t)sidx * CIN + lane * 2];
        gx += b2f(v.x); gy += b2f(v.y);
      }
    } else {
#pragma unroll
      for (int j = 0; j < 16; ++j) {
        int eidx = __shfl(comb, j);
        int sidx = __shfl(comb, 16 + j);
        float ev = eattr[(size_t)eidx * CEC + lane];
        ushort2 v = *(const ushort2*)&xb[(size_t)sidx * CIN + lane * 2];
        if (j < rem) { ea_acc += ev; gx += b2f(v.x); gy += b2f(v.y); }
      }
    }
  }
  ushort eb = f2b(ea_acc);
  A1[(size_t)node * K1 + 2 * CIN + lane] = eb;
  A23[(size_t)node * K23 + 2 * CHID + lane] = eb;
  ushort2 go = { f2b(gx), f2b(gy) };
  *(ushort2*)&A1[(size_t)node * K1 + CIN + lane * 2] = go;
}

// layers 2/3: G from hb (Kh=256) -> A23[:, 256:512]
__global__ __launch_bounds__(256) void k_gather256(const ushort* __restrict__ hb, const int* __restrict__ ptr,
                                                   const int* __restrict__ srcs, ushort* __restrict__ A23) {
  int node = blockIdx.x * 4 + (threadIdx.x >> 6);
  int lane = threadIdx.x & 63;
  ushort4 own = *(const ushort4*)&hb[(size_t)node * CHID + lane * 4];
  float ax = b2f(own.x), ay = b2f(own.y), az = b2f(own.z), aw = b2f(own.w);
  int s = ptr[node], e = ptr[node + 1];
  for (int k0 = s; k0 < e; k0 += 16) {
    int rem = e - k0;
    int myi = (lane < 16 && lane < rem) ? srcs[k0 + lane] : 0;
    if (rem >= 16) {
#pragma unroll
      for (int j = 0; j < 16; ++j) {
        int idx = __shfl(myi, j);
        ushort4 v = *(const ushort4*)&hb[(size_t)idx * CHID + lane * 4];
        ax += b2f(v.x); ay += b2f(v.y); az += b2f(v.z); aw += b2f(v.w);
      }
    } else {
#pragma unroll
      for (int j = 0; j < 16; ++j) {
        int idx = __shfl(myi, j);
        ushort4 v = *(const ushort4*)&hb[(size_t)idx * CHID + lane * 4];
        if (j < rem) { ax += b2f(v.x); ay += b2f(v.y); az += b2f(v.z); aw += b2f(v.w); }
      }
    }
  }
  ushort4 o = { f2b(ax), f2b(ay), f2b(az), f2b(aw) };
  *(ushort4*)&A23[(size_t)node * K23 + CHID + lane * 4] = o;
}

// all three weight transposes in one launch: flat over 256*(K1+2*K23) = 376832 = 1472*256
__global__ __launch_bounds__(256) void k_wt3(const float* __restrict__ W1, const float* __restrict__ W2,
                                             const float* __restrict__ W3, ushort* __restrict__ Wt1,
                                             ushort* __restrict__ Wt2, ushort* __restrict__ Wt3) {
  int i = blockIdx.x * 256 + threadIdx.x;
  const float* W; ushort* Wt; int Ktot; int j = i;
  if (j < 256 * K1) { W = W1; Wt = Wt1; Ktot = K1; }
  else {
    j -= 256 * K1;
    if (j < 256 * K23) { W = W2; Wt = Wt2; Ktot = K23; }
    else { j -= 256 * K23; W = W3; Wt = Wt3; Ktot = K23; }
  }
  int n = j / Ktot;
  int k = j - n * Ktot;
  Wt[j] = f2b(W[(size_t)k * CHID + n]);
}

// ---------------- MFMA GEMM (M=NN, N=256, K=Ktot) + fused bias/relu/BN-stats ----------------
__global__ __launch_bounds__(256) void k_gemm(const ushort* __restrict__ Ag, const ushort* __restrict__ Wt,
                                              const float* __restrict__ bias, const float* __restrict__ degf,
                                              float* __restrict__ out, float* __restrict__ colsum,
                                              float* __restrict__ colsq, int Ktot) {
  __shared__ ushort As[128 * 40];  // 128 rows x 32 k, stride 40
  __shared__ ushort Bs[64 * 40];   // 64 n x 32 k
  const int bm = blockIdx.x * 128;
  const int bn = blockIdx.y * 64;
  const int tid = threadIdx.x;
  const int w = tid >> 6;
  const int lane = tid & 63;
  const int ln = lane & 15;
  const int quad = lane >> 4;

  f4 acc[2][4];
#pragma unroll
  for (int mf = 0; mf < 2; ++mf)
#pragma unroll
    for (int nf = 0; nf < 4; ++nf) acc[mf][nf] = (f4){0.f, 0.f, 0.f, 0.f};

  const int rA = tid >> 1;
  const int hk = (tid & 1) << 4;  // 0 or 16
  const int rowA = bm + rA;
  const int nB = tid >> 2;
  const int kq = (tid & 3) << 3;  // 0,8,16,24

  for (int k0 = 0; k0 < Ktot; k0 += 32) {
    uint4 v0 = {0, 0, 0, 0}, v1 = {0, 0, 0, 0};
    if (rowA < NN) {
      const uint4* p = (const uint4*)(Ag + (size_t)rowA * Ktot + k0 + hk);
      v0 = p[0]; v1 = p[1];
    }
    *(uint4*)&As[rA * 40 + hk] = v0;
    *(uint4*)&As[rA * 40 + hk + 8] = v1;
    uint4 bv = *(const uint4*)(Wt + (size_t)(bn + nB) * Ktot + k0 + kq);
    *(uint4*)&Bs[nB * 40 + kq] = bv;
    __syncthreads();

    sfrag a0 = *(const sfrag*)&As[(w * 32 + ln) * 40 + quad * 8];
    sfrag a1 = *(const sfrag*)&As[(w * 32 + 16 + ln) * 40 + quad * 8];
#pragma unroll
    for (int nf = 0; nf < 4; ++nf) {
      sfrag b = *(const sfrag*)&Bs[(nf * 16 + ln) * 40 + quad * 8];
      acc[0][nf] = __builtin_amdgcn_mfma_f32_16x16x32_bf16(a0, b, acc[0][nf], 0, 0, 0);
      acc[1][nf] = __builtin_amdgcn_mfma_f32_16x16x32_bf16(a1, b, acc[1][nf], 0, 0, 0);
    }
    __syncthreads();
  }

  float bcol[4];
#pragma unroll
  for (int nf = 0; nf < 4; ++nf) bcol[nf] = bias[bn + nf * 16 + ln];
  float ssum[4] = {0.f, 0.f, 0.f, 0.f}, sqq[4] = {0.f, 0.f, 0.f, 0.f};
#pragma unroll
  for (int mf = 0; mf < 2; ++mf) {
    int rbase = bm + w * 32 + mf * 16 + quad * 4;
#pragma unroll
    for (int r = 0; r < 4; ++r) {
      int row = rbase + r;
      bool valid = row < NN;
      float d = valid ? degf[row] : 0.f;
#pragma unroll
      for (int nf = 0; nf < 4; ++nf) {
        float v = fmaxf(acc[mf][nf][r] + d * bcol[nf], 0.f);
        if (valid) {
          out[(size_t)row * CHID + bn + nf * 16 + ln] = v;
          ssum[nf] += v;
          sqq[nf] += v * v;
        }
      }
    }
  }
#pragma unroll
  for (int nf = 0; nf < 4; ++nf) {
    float s = ssum[nf], q = sqq[nf];
    s += __shfl_xor(s, 16); s += __shfl_xor(s, 32);
    q += __shfl_xor(q, 16); q += __shfl_xor(q, 32);
    if (quad == 0) {
      atomicAdd(&colsum[bn + nf * 16 + ln], s);
      atomicAdd(&colsq[bn + nf * 16 + ln], q);
    }
  }
}

// ---------------- BN apply (layers 1,2): inline bnfin; writes hb + next A-panel only ----------------
__global__ __launch_bounds__(256) void k_bnapply(const float4* __restrict__ t, const float* __restrict__ colsum,
                                                 const float* __restrict__ colsq, const float* __restrict__ g,
                                                 const float* __restrict__ be, ushort* __restrict__ Apanel,
                                                 ushort* __restrict__ hb, const float* __restrict__ degf) {
  int gid = blockIdx.x * 256 + threadIdx.x;  // NN*64
  int node = gid >> 6;
  int c4 = (gid & 63) << 2;
  float sc[4], sh[4];
#pragma unroll
  for (int j = 0; j < 4; ++j) {
    int c = c4 + j;
    float mu = colsum[c] * (1.f / (float)NN);
    float var = colsq[c] * (1.f / (float)NN) - mu * mu;
    float inv = rsqrtf(var + 1e-5f);
    sc[j] = g[c] * inv;
    sh[j] = be[c] - mu * sc[j];
  }
  float4 v = t[gid];
  float o0 = fmaxf(fmaf(v.x, sc[0], sh[0]), 0.f);
  float o1 = fmaxf(fmaf(v.y, sc[1], sh[1]), 0.f);
  float o2 = fmaxf(fmaf(v.z, sc[2], sh[2]), 0.f);
  float o3 = fmaxf(fmaf(v.w, sc[3], sh[3]), 0.f);
  ushort4 ho = { f2b(o0), f2b(o1), f2b(o2), f2b(o3) };
  *(ushort4*)&hb[(size_t)node * CHID + c4] = ho;
  float d = degf[node];
  ushort4 ao = { f2b(d * o0), f2b(d * o1), f2b(d * o2), f2b(d * o3) };
  *(ushort4*)&Apanel[(size_t)node * K23 + c4] = ao;
}

// ---------------- layer-3 BN + relu + segment pool, fused ----------------
__global__ __launch_bounds__(256) void k_poolbn(const float* __restrict__ t, const float* __restrict__ colsum,
                                                const float* __restrict__ colsq, const float* __restrict__ g,
                                                const float* __restrict__ be, const int* __restrict__ batch,
                                                float* __restrict__ pooled) {
  __shared__ int bsh[64];
  int r0 = blockIdx.x * 64;
  int c = threadIdx.x;
  int rows = min(64, NN - r0);
  if (c < rows) bsh[c] = batch[r0 + c];
  __syncthreads();
  float mu = colsum[c] * (1.f / (float)NN);
  float var = colsq[c] * (1.f / (float)NN) - mu * mu;
  float inv = rsqrtf(var + 1e-5f);
  float sc = g[c] * inv;
  float sh = be[c] - mu * sc;
  float acc = 0.f;
  int cur = bsh[0];
  for (int r = 0; r < rows; ++r) {
    int gg = bsh[r];
    if (gg != cur) {
      atomicAdd(&pooled[cur * CHID + c], acc);
      acc = 0.f;
      cur = gg;
    }
    acc += fmaxf(fmaf(t[(size_t)(r0 + r) * CHID + c], sc, sh), 0.f);
  }
  atomicAdd(&pooled[cur * CHID + c], acc);
}

// ---------------- MLP head ----------------
__global__ __launch_bounds__(512) void k_mlp(const float* __restrict__ pooled, const float* __restrict__ counts,
                                             const float* __restrict__ nb, const float* __restrict__ w1,
                                             const float* __restrict__ b1, const float* __restrict__ w2,
                                             const float* __restrict__ b2, float* __restrict__ out) {
  int g = blockIdx.x;
  int t = threadIdx.x;
  __shared__ float zin[CHID + 1 + CIN];  // 385
  __shared__ float red[512];
  if (t < CHID) zin[t] = pooled[g * CHID + t];
  else if (t == CHID) zin[CHID] = counts[g] * 0.025f;  // / MAX_SIZE(40)
  else if (t < CHID + 1 + CIN) zin[t] = nb[g * CIN + (t - CHID - 1)];
  __syncthreads();
  float acc = b1[t];
  for (int k = 0; k < CHID + 1 + CIN; ++k) acc = fmaf(zin[k], w1[k * CMLP + t], acc);
  float z = fmaxf(acc, 0.f);
#pragma unroll
  for (int n = 0; n < CNC; ++n) {
    red[t] = z * w2[t * CNC + n];
    __syncthreads();
    for (int s = 256; s > 0; s >>= 1) {
      if (t < s) red[t] += red[t + s];
      __syncthreads();
    }
    if (t == 0) out[g * CNC + n] = red[0] + b2[n];
    __syncthreads();
  }
}

// ---------------- launch ----------------

extern "C" void kernel_launch(void* const* d_in, const int* in_sizes, int n_in,
                              void* d_out, int out_size, void* d_ws, size_t ws_size,
                              hipStream_t stream) {
  const float* x     = (const float*)d_in[0];
  const int*   ei    = (const int*)d_in[1];
  const float* eattr = (const float*)d_in[2];
  const int*   batch = (const int*)d_in[3];
  const float* nbr   = (const float*)d_in[4];
  const float* W1 = (const float*)d_in[5];
  const float* b1 = (const float*)d_in[6];
  const float* g1 = (const float*)d_in[7];
  const float* be1 = (const float*)d_in[8];
  const float* W2 = (const float*)d_in[9];
  const float* b2 = (const float*)d_in[10];
  const float* g2 = (const float*)d_in[11];
  const float* be2 = (const float*)d_in[12];
  const float* W3 = (const float*)d_in[13];
  const float* b3 = (const float*)d_in[14];
  const float* g3 = (const float*)d_in[15];
  const float* be3 = (const float*)d_in[16];
  const float* fc1w = (const float*)d_in[17];
  const float* fc1b = (const float*)d_in[18];
  const float* fc2w = (const float*)d_in[19];
  const float* fc2b = (const float*)d_in[20];
  float* out = (float*)d_out;

  char* ws = (char*)d_ws;
  size_t off = 0;
  auto alloc = [&](size_t bytes) {
    void* p = ws + off;
    off = (off + bytes + 255) & ~(size_t)255;
    return p;
  };
  int*    ptr    = (int*)alloc((NN + 1) * sizeof(int));
  int*    pos    = (int*)alloc(NN * sizeof(int));
  float*  degf   = (float*)alloc(NN * sizeof(float));
  int*    eid    = (int*)alloc(NE * sizeof(int));
  int*    srcs   = (int*)alloc(NE * sizeof(int));
  ushort* A1     = (ushort*)alloc((size_t)NN * K1 * sizeof(ushort));
  ushort* A23    = (ushort*)alloc((size_t)NN * K23 * sizeof(ushort));
  ushort* Wt1    = (ushort*)alloc((size_t)256 * K1 * sizeof(ushort));
  ushort* Wt2    = (ushort*)alloc((size_t)256 * K23 * sizeof(ushort));
  ushort* Wt3    = (ushort*)alloc((size_t)256 * K23 * sizeof(ushort));
  ushort* xb     = (ushort*)alloc((size_t)NN * CIN * sizeof(ushort));
  ushort* hb     = (ushort*)alloc((size_t)NN * CHID * sizeof(ushort));
  float*  tmp    = (float*)alloc((size_t)NN * CHID * sizeof(float));
  float*  stats  = (float*)alloc(6 * CHID * sizeof(float));  // [layer][sum|sq][256]
  float*  pooled = (float*)alloc((size_t)NB * CHID * sizeof(float));
  float*  counts = (float*)alloc(NB * sizeof(float));
  (void)ws_size; (void)n_in; (void)in_sizes; (void)out_size;

  float* cs1 = stats + 0 * 512, *cq1 = stats + 0 * 512 + 256;
  float* cs2 = stats + 1 * 512, *cq2 = stats + 1 * 512 + 256;
  float* cs3 = stats + 2 * 512, *cq3 = stats + 2 * 512 + 256;

  // CSR + static aggregates (16 dispatches total)
  k_init<<<cdiv(NB * CHID, 256), 256, 0, stream>>>(ptr, pooled, counts, stats);
  k_count<<<1250 + 40, 256, 0, stream>>>(ei, ptr, batch, counts);
  k_scan<<<1, 1024, 0, stream>>>(ptr, pos, degf);
  k_fill<<<1250, 256, 0, stream>>>(ei, pos, eid, srcs);
  k_prep<<<1250, 256, 0, stream>>>((const float4*)x, degf, A1, xb);
  k_eag<<<NN / 4, 256, 0, stream>>>(eattr, xb, ptr, eid, srcs, A1, A23);
  k_wt3<<<1472, 256, 0, stream>>>(W1, W2, W3, Wt1, Wt2, Wt3);

  dim3 ggrid(cdiv(NN, 128), CHID / 64);

  // layer 1
  k_gemm<<<ggrid, 256, 0, stream>>>(A1, Wt1, b1, degf, tmp, cs1, cq1, K1);
  k_bnapply<<<cdiv(NN * 64, 256), 256, 0, stream>>>((const float4*)tmp, cs1, cq1, g1, be1, A23, hb, degf);

  // layer 2
  k_gather256<<<NN / 4, 256, 0, stream>>>(hb, ptr, srcs, A23);
  k_gemm<<<ggrid, 256, 0, stream>>>(A23, Wt2, b2, degf, tmp, cs2, cq2, K23);
  k_bnapply<<<cdiv(NN * 64, 256), 256, 0, stream>>>((const float4*)tmp, cs2, cq2, g2, be2, A23, hb, degf);

  // layer 3
  k_gather256<<<NN / 4, 256, 0, stream>>>(hb, ptr, srcs, A23);
  k_gemm<<<ggrid, 256, 0, stream>>>(A23, Wt3, b3, degf, tmp, cs3, cq3, K23);
  k_poolbn<<<cdiv(NN, 64), 256, 0, stream>>>(tmp, cs3, cq3, g3, be3, batch, pooled);

  // MLP head
  k_mlp<<<NB, 512, 0, stream>>>(pooled, counts, nbr, fc1w, fc1b, fc2w, fc2b, out);
}

// Round 5
// 424.539 us; speedup vs baseline: 1.4037x; 1.0421x over previous
//
#include <hip/hip_runtime.h>

#define NN 10000      // nodes
#define NE 320000     // edges (before self-loops)
#define NB 64         // graphs
#define CIN 128       // in_channels
#define CEC 64        // edge_channels
#define CHID 256      // hidden
#define CMLP 512
#define CNC 4
#define K1 (2 * CIN + CEC)    // 320
#define K23 (2 * CHID + CEC)  // 576

static __host__ int cdiv(int a, int b) { return (a + b - 1) / b; }

typedef short sfrag __attribute__((ext_vector_type(8)));   // 8 bf16 in 4 VGPRs
typedef float f4 __attribute__((ext_vector_type(4)));

static __device__ __forceinline__ ushort f2b(float f) {
  union { float f; unsigned u; } v; v.f = f;
  unsigned r = (v.u + 0x7fffu + ((v.u >> 16) & 1u)) >> 16;
  return (ushort)r;
}
static __device__ __forceinline__ float b2f(ushort u) {
  union { unsigned u; float f; } v; v.u = ((unsigned)u) << 16;
  return v.f;
}

// ---------------- setup kernels ----------------

__global__ __launch_bounds__(256) void k_init(int* __restrict__ ptr, float* __restrict__ pooled,
                                              float* __restrict__ counts, float* __restrict__ stats) {
  int i = blockIdx.x * 256 + threadIdx.x;
  if (i <= NN) ptr[i] = 0;
  if (i < NB * CHID) pooled[i] = 0.f;
  if (i < NB) counts[i] = 0.f;
  if (i < 6 * CHID) stats[i] = 0.f;
}

// blocks [0,1250): edge-degree histogram; blocks [1250,1290): batch histogram -> counts
__global__ __launch_bounds__(256) void k_count(const int* __restrict__ ei, int* __restrict__ ptr,
                                               const int* __restrict__ batch, float* __restrict__ counts) {
  int b = blockIdx.x;
  if (b < 1250) {
    int e = b * 256 + threadIdx.x;  // 1250*256 == NE exactly
    atomicAdd(&ptr[ei[NE + e] + 1], 1);
  } else {
    __shared__ int hist[NB];
    if (threadIdx.x < NB) hist[threadIdx.x] = 0;
    __syncthreads();
    int n = (b - 1250) * 256 + threadIdx.x;
    if (n < NN) atomicAdd(&hist[batch[n]], 1);
    __syncthreads();
    if (threadIdx.x < NB && hist[threadIdx.x]) atomicAdd(&counts[threadIdx.x], (float)hist[threadIdx.x]);
  }
}

// single-block inclusive scan over ptr[0..NN] + fused pos/degf writeout
__global__ __launch_bounds__(1024) void k_scan(int* __restrict__ ptr, int* __restrict__ pos,
                                               float* __restrict__ degf) {
  __shared__ int wsum[16];
  __shared__ int chtot;
  int carry = 0;
  const int n1 = NN + 1;
  const int lane = threadIdx.x & 63;
  const int wid = threadIdx.x >> 6;
  for (int base = 0; base < n1; base += 1024) {
    int i = base + threadIdx.x;
    int v = (i < n1) ? ptr[i] : 0;
    int sc = v;
#pragma unroll
    for (int d = 1; d < 64; d <<= 1) {
      int t = __shfl_up(sc, d);
      if (lane >= d) sc += t;
    }
    if (lane == 63) wsum[wid] = sc;
    __syncthreads();
    if (wid == 0 && lane < 16) {
      int ws = wsum[lane];
      int s2 = ws;
#pragma unroll
      for (int d = 1; d < 16; d <<= 1) {
        int t = __shfl_up(s2, d);
        if (lane >= d) s2 += t;
      }
      wsum[lane] = s2 - ws;  // exclusive
      if (lane == 15) chtot = s2;
    }
    __syncthreads();
    if (i < n1) ptr[i] = sc + wsum[wid] + carry;
    carry += chtot;
    __syncthreads();
  }
  for (int i = threadIdx.x; i < NN; i += 1024) {
    int p = ptr[i], q = ptr[i + 1];
    pos[i] = p;
    degf[i] = (float)(q - p + 1);  // +1 self-loop
  }
}

// counting-sort placement: srcs in CSR order + perm (original e -> sorted slot)
__global__ __launch_bounds__(256) void k_fill(const int* __restrict__ ei, int* __restrict__ pos,
                                              int* __restrict__ perm, int* __restrict__ srcs) {
  int e = blockIdx.x * 256 + threadIdx.x;  // 1250*256 == NE
  int d = ei[NE + e];
  int idx = atomicAdd(&pos[d], 1);
  perm[e] = idx;
  srcs[idx] = ei[e];
}

// permute edge_attr into CSR order, fp32 -> bf16. Streaming reads, scattered 128B writes.
__global__ __launch_bounds__(256) void k_perm(const float4* __restrict__ eattr, const int* __restrict__ perm,
                                              ushort* __restrict__ eattrs) {
  int tid = threadIdx.x;
  int e = blockIdx.x * 16 + (tid >> 4);  // 20000 blocks x 16 edges
  int c0 = (tid & 15) << 2;
  float4 v = eattr[(size_t)e * 16 + (c0 >> 2)];
  int sp = perm[e];
  ushort4 o = { f2b(v.x), f2b(v.y), f2b(v.z), f2b(v.w) };
  *(ushort4*)&eattrs[(size_t)sp * CEC + c0] = o;
}

// A1[:, 0:128] = bf16(degf * x); xb = bf16(x)
__global__ __launch_bounds__(256) void k_prep(const float4* __restrict__ x, const float* __restrict__ degf,
                                              ushort* __restrict__ A1, ushort* __restrict__ xb) {
  int gid = blockIdx.x * 256 + threadIdx.x;  // NN*32 = 320000 = 1250*256
  int node = gid >> 5;
  int c4 = (gid & 31) << 2;
  float d = degf[node];
  float4 v = x[gid];
  ushort4 o = { f2b(d * v.x), f2b(d * v.y), f2b(d * v.z), f2b(d * v.w) };
  *(ushort4*)&A1[(size_t)node * K1 + c4] = o;
  ushort4 xo = { f2b(v.x), f2b(v.y), f2b(v.z), f2b(v.w) };
  *(ushort4*)&xb[(size_t)node * CIN + c4] = xo;
}

// fused: ea_sum (streaming over CSR-ordered eattrs) + layer-1 gather of x. Wave per node.
__global__ __launch_bounds__(256) void k_eag(const ushort* __restrict__ eattrs, const ushort* __restrict__ xb,
                                             const int* __restrict__ ptr, const int* __restrict__ srcs,
                                             ushort* __restrict__ A1, ushort* __restrict__ A23) {
  int node = blockIdx.x * 4 + (threadIdx.x >> 6);
  int lane = threadIdx.x & 63;
  int s = ptr[node], e = ptr[node + 1];

  // edge-attr sum: contiguous bf16 rows, 4-row unrolled independent loads
  float ea_acc = 1.0f;  // PyG self-loop edge_attr fill
  for (int k = s; k < e; k += 4) {
    int r1 = min(k + 1, e - 1), r2 = min(k + 2, e - 1), r3 = min(k + 3, e - 1);
    float v0 = b2f(eattrs[(size_t)k * CEC + lane]);
    float t1 = b2f(eattrs[(size_t)r1 * CEC + lane]);
    float t2 = b2f(eattrs[(size_t)r2 * CEC + lane]);
    float t3 = b2f(eattrs[(size_t)r3 * CEC + lane]);
    ea_acc += v0;
    if (k + 1 < e) ea_acc += t1;
    if (k + 2 < e) ea_acc += t2;
    if (k + 3 < e) ea_acc += t3;
  }
  ushort eb = f2b(ea_acc);
  A1[(size_t)node * K1 + 2 * CIN + lane] = eb;
  A23[(size_t)node * K23 + 2 * CHID + lane] = eb;

  // layer-1 gather: G = x_i + sum x_src (bf16 table, shfl-broadcast indices)
  ushort2 own = *(const ushort2*)&xb[(size_t)node * CIN + lane * 2];
  float gx = b2f(own.x), gy = b2f(own.y);
  for (int k0 = s; k0 < e; k0 += 16) {
    int rem = e - k0;
    int myi = (lane < 16 && lane < rem) ? srcs[k0 + lane] : 0;
    if (rem >= 16) {
#pragma unroll
      for (int j = 0; j < 16; ++j) {
        int idx = __shfl(myi, j);
        ushort2 v = *(const ushort2*)&xb[(size_t)idx * CIN + lane * 2];
        gx += b2f(v.x); gy += b2f(v.y);
      }
    } else {
#pragma unroll
      for (int j = 0; j < 16; ++j) {
        int idx = __shfl(myi, j);
        ushort2 v = *(const ushort2*)&xb[(size_t)idx * CIN + lane * 2];
        if (j < rem) { gx += b2f(v.x); gy += b2f(v.y); }
      }
    }
  }
  ushort2 go = { f2b(gx), f2b(gy) };
  *(ushort2*)&A1[(size_t)node * K1 + CIN + lane * 2] = go;
}

// layers 2/3 gather, channel-split (coff = 0 or 128): slice is L2-resident (2.56 MB/XCD)
__global__ __launch_bounds__(256) void k_gather256(const ushort* __restrict__ hb, const int* __restrict__ ptr,
                                                   const int* __restrict__ srcs, ushort* __restrict__ A23,
                                                   int coff) {
  int node = blockIdx.x * 4 + (threadIdx.x >> 6);
  int lane = threadIdx.x & 63;
  const ushort* hbl = hb + coff + lane * 2;
  ushort2 own = *(const ushort2*)&hbl[(size_t)node * CHID];
  float ax = b2f(own.x), ay = b2f(own.y);
  int s = ptr[node], e = ptr[node + 1];
  for (int k0 = s; k0 < e; k0 += 16) {
    int rem = e - k0;
    int myi = (lane < 16 && lane < rem) ? srcs[k0 + lane] : 0;
    if (rem >= 16) {
#pragma unroll
      for (int j = 0; j < 16; ++j) {
        int idx = __shfl(myi, j);
        ushort2 v = *(const ushort2*)&hbl[(size_t)idx * CHID];
        ax += b2f(v.x); ay += b2f(v.y);
      }
    } else {
#pragma unroll
      for (int j = 0; j < 16; ++j) {
        int idx = __shfl(myi, j);
        ushort2 v = *(const ushort2*)&hbl[(size_t)idx * CHID];
        if (j < rem) { ax += b2f(v.x); ay += b2f(v.y); }
      }
    }
  }
  ushort2 o = { f2b(ax), f2b(ay) };
  *(ushort2*)&A23[(size_t)node * K23 + CHID + coff + lane * 2] = o;
}

// all three weight transposes in one launch: flat over 256*(K1+2*K23) = 376832 = 1472*256
__global__ __launch_bounds__(256) void k_wt3(const float* __restrict__ W1, const float* __restrict__ W2,
                                             const float* __restrict__ W3, ushort* __restrict__ Wt1,
                                             ushort* __restrict__ Wt2, ushort* __restrict__ Wt3) {
  int i = blockIdx.x * 256 + threadIdx.x;
  const float* W; ushort* Wt; int Ktot; int j = i;
  if (j < 256 * K1) { W = W1; Wt = Wt1; Ktot = K1; }
  else {
    j -= 256 * K1;
    if (j < 256 * K23) { W = W2; Wt = Wt2; Ktot = K23; }
    else { j -= 256 * K23; W = W3; Wt = Wt3; Ktot = K23; }
  }
  int n = j / Ktot;
  int k = j - n * Ktot;
  Wt[j] = f2b(W[(size_t)k * CHID + n]);
}

// ---------------- MFMA GEMM (M=NN, N=256, K=Ktot) + fused bias/relu/BN-stats ----------------
__global__ __launch_bounds__(256) void k_gemm(const ushort* __restrict__ Ag, const ushort* __restrict__ Wt,
                                              const float* __restrict__ bias, const float* __restrict__ degf,
                                              float* __restrict__ out, float* __restrict__ colsum,
                                              float* __restrict__ colsq, int Ktot) {
  __shared__ ushort As[128 * 40];  // 128 rows x 32 k, stride 40
  __shared__ ushort Bs[64 * 40];   // 64 n x 32 k
  const int bm = blockIdx.x * 128;
  const int bn = blockIdx.y * 64;
  const int tid = threadIdx.x;
  const int w = tid >> 6;
  const int lane = tid & 63;
  const int ln = lane & 15;
  const int quad = lane >> 4;

  f4 acc[2][4];
#pragma unroll
  for (int mf = 0; mf < 2; ++mf)
#pragma unroll
    for (int nf = 0; nf < 4; ++nf) acc[mf][nf] = (f4){0.f, 0.f, 0.f, 0.f};

  const int rA = tid >> 1;
  const int hk = (tid & 1) << 4;  // 0 or 16
  const int rowA = bm + rA;
  const int nB = tid >> 2;
  const int kq = (tid & 3) << 3;  // 0,8,16,24

  for (int k0 = 0; k0 < Ktot; k0 += 32) {
    uint4 v0 = {0, 0, 0, 0}, v1 = {0, 0, 0, 0};
    if (rowA < NN) {
      const uint4* p = (const uint4*)(Ag + (size_t)rowA * Ktot + k0 + hk);
      v0 = p[0]; v1 = p[1];
    }
    *(uint4*)&As[rA * 40 + hk] = v0;
    *(uint4*)&As[rA * 40 + hk + 8] = v1;
    uint4 bv = *(const uint4*)(Wt + (size_t)(bn + nB) * Ktot + k0 + kq);
    *(uint4*)&Bs[nB * 40 + kq] = bv;
    __syncthreads();

    sfrag a0 = *(const sfrag*)&As[(w * 32 + ln) * 40 + quad * 8];
    sfrag a1 = *(const sfrag*)&As[(w * 32 + 16 + ln) * 40 + quad * 8];
#pragma unroll
    for (int nf = 0; nf < 4; ++nf) {
      sfrag b = *(const sfrag*)&Bs[(nf * 16 + ln) * 40 + quad * 8];
      acc[0][nf] = __builtin_amdgcn_mfma_f32_16x16x32_bf16(a0, b, acc[0][nf], 0, 0, 0);
      acc[1][nf] = __builtin_amdgcn_mfma_f32_16x16x32_bf16(a1, b, acc[1][nf], 0, 0, 0);
    }
    __syncthreads();
  }

  float bcol[4];
#pragma unroll
  for (int nf = 0; nf < 4; ++nf) bcol[nf] = bias[bn + nf * 16 + ln];
  float ssum[4] = {0.f, 0.f, 0.f, 0.f}, sqq[4] = {0.f, 0.f, 0.f, 0.f};
#pragma unroll
  for (int mf = 0; mf < 2; ++mf) {
    int rbase = bm + w * 32 + mf * 16 + quad * 4;
#pragma unroll
    for (int r = 0; r < 4; ++r) {
      int row = rbase + r;
      bool valid = row < NN;
      float d = valid ? degf[row] : 0.f;
#pragma unroll
      for (int nf = 0; nf < 4; ++nf) {
        float v = fmaxf(acc[mf][nf][r] + d * bcol[nf], 0.f);
        if (valid) {
          out[(size_t)row * CHID + bn + nf * 16 + ln] = v;
          ssum[nf] += v;
          sqq[nf] += v * v;
        }
      }
    }
  }
#pragma unroll
  for (int nf = 0; nf < 4; ++nf) {
    float s = ssum[nf], q = sqq[nf];
    s += __shfl_xor(s, 16); s += __shfl_xor(s, 32);
    q += __shfl_xor(q, 16); q += __shfl_xor(q, 32);
    if (quad == 0) {
      atomicAdd(&colsum[bn + nf * 16 + ln], s);
      atomicAdd(&colsq[bn + nf * 16 + ln], q);
    }
  }
}

// ---------------- BN apply (layers 1,2): inline bnfin; writes hb + next A-panel only ----------------
__global__ __launch_bounds__(256) void k_bnapply(const float4* __restrict__ t, const float* __restrict__ colsum,
                                                 const float* __restrict__ colsq, const float* __restrict__ g,
                                                 const float* __restrict__ be, ushort* __restrict__ Apanel,
                                                 ushort* __restrict__ hb, const float* __restrict__ degf) {
  int gid = blockIdx.x * 256 + threadIdx.x;  // NN*64
  int node = gid >> 6;
  int c4 = (gid & 63) << 2;
  float sc[4], sh[4];
#pragma unroll
  for (int j = 0; j < 4; ++j) {
    int c = c4 + j;
    float mu = colsum[c] * (1.f / (float)NN);
    float var = colsq[c] * (1.f / (float)NN) - mu * mu;
    float inv = rsqrtf(var + 1e-5f);
    sc[j] = g[c] * inv;
    sh[j] = be[c] - mu * sc[j];
  }
  float4 v = t[gid];
  float o0 = fmaxf(fmaf(v.x, sc[0], sh[0]), 0.f);
  float o1 = fmaxf(fmaf(v.y, sc[1], sh[1]), 0.f);
  float o2 = fmaxf(fmaf(v.z, sc[2], sh[2]), 0.f);
  float o3 = fmaxf(fmaf(v.w, sc[3], sh[3]), 0.f);
  ushort4 ho = { f2b(o0), f2b(o1), f2b(o2), f2b(o3) };
  *(ushort4*)&hb[(size_t)node * CHID + c4] = ho;
  float d = degf[node];
  ushort4 ao = { f2b(d * o0), f2b(d * o1), f2b(d * o2), f2b(d * o3) };
  *(ushort4*)&Apanel[(size_t)node * K23 + c4] = ao;
}

// ---------------- layer-3 BN + relu + segment pool, fused ----------------
__global__ __launch_bounds__(256) void k_poolbn(const float* __restrict__ t, const float* __restrict__ colsum,
                                                const float* __restrict__ colsq, const float* __restrict__ g,
                                                const float* __restrict__ be, const int* __restrict__ batch,
                                                float* __restrict__ pooled) {
  __shared__ int bsh[64];
  int r0 = blockIdx.x * 64;
  int c = threadIdx.x;
  int rows = min(64, NN - r0);
  if (c < rows) bsh[c] = batch[r0 + c];
  __syncthreads();
  float mu = colsum[c] * (1.f / (float)NN);
  float var = colsq[c] * (1.f / (float)NN) - mu * mu;
  float inv = rsqrtf(var + 1e-5f);
  float sc = g[c] * inv;
  float sh = be[c] - mu * sc;
  float acc = 0.f;
  int cur = bsh[0];
  for (int r = 0; r < rows; ++r) {
    int gg = bsh[r];
    if (gg != cur) {
      atomicAdd(&pooled[cur * CHID + c], acc);
      acc = 0.f;
      cur = gg;
    }
    acc += fmaxf(fmaf(t[(size_t)(r0 + r) * CHID + c], sc, sh), 0.f);
  }
  atomicAdd(&pooled[cur * CHID + c], acc);
}

// ---------------- MLP head ----------------
__global__ __launch_bounds__(512) void k_mlp(const float* __restrict__ pooled, const float* __restrict__ counts,
                                             const float* __restrict__ nb, const float* __restrict__ w1,
                                             const float* __restrict__ b1, const float* __restrict__ w2,
                                             const float* __restrict__ b2, float* __restrict__ out) {
  int g = blockIdx.x;
  int t = threadIdx.x;
  __shared__ float zin[CHID + 1 + CIN];  // 385
  __shared__ float red[512];
  if (t < CHID) zin[t] = pooled[g * CHID + t];
  else if (t == CHID) zin[CHID] = counts[g] * 0.025f;  // / MAX_SIZE(40)
  else if (t < CHID + 1 + CIN) zin[t] = nb[g * CIN + (t - CHID - 1)];
  __syncthreads();
  float acc = b1[t];
  for (int k = 0; k < CHID + 1 + CIN; ++k) acc = fmaf(zin[k], w1[k * CMLP + t], acc);
  float z = fmaxf(acc, 0.f);
#pragma unroll
  for (int n = 0; n < CNC; ++n) {
    red[t] = z * w2[t * CNC + n];
    __syncthreads();
    for (int s = 256; s > 0; s >>= 1) {
      if (t < s) red[t] += red[t + s];
      __syncthreads();
    }
    if (t == 0) out[g * CNC + n] = red[0] + b2[n];
    __syncthreads();
  }
}

// ---------------- launch ----------------

extern "C" void kernel_launch(void* const* d_in, const int* in_sizes, int n_in,
                              void* d_out, int out_size, void* d_ws, size_t ws_size,
                              hipStream_t stream) {
  const float* x     = (const float*)d_in[0];
  const int*   ei    = (const int*)d_in[1];
  const float* eattr = (const float*)d_in[2];
  const int*   batch = (const int*)d_in[3];
  const float* nbr   = (const float*)d_in[4];
  const float* W1 = (const float*)d_in[5];
  const float* b1 = (const float*)d_in[6];
  const float* g1 = (const float*)d_in[7];
  const float* be1 = (const float*)d_in[8];
  const float* W2 = (const float*)d_in[9];
  const float* b2 = (const float*)d_in[10];
  const float* g2 = (const float*)d_in[11];
  const float* be2 = (const float*)d_in[12];
  const float* W3 = (const float*)d_in[13];
  const float* b3 = (const float*)d_in[14];
  const float* g3 = (const float*)d_in[15];
  const float* be3 = (const float*)d_in[16];
  const float* fc1w = (const float*)d_in[17];
  const float* fc1b = (const float*)d_in[18];
  const float* fc2w = (const float*)d_in[19];
  const float* fc2b = (const float*)d_in[20];
  float* out = (float*)d_out;

  char* ws = (char*)d_ws;
  size_t off = 0;
  auto alloc = [&](size_t bytes) {
    void* p = ws + off;
    off = (off + bytes + 255) & ~(size_t)255;
    return p;
  };
  int*    ptr    = (int*)alloc((NN + 1) * sizeof(int));
  int*    pos    = (int*)alloc(NN * sizeof(int));
  float*  degf   = (float*)alloc(NN * sizeof(float));
  int*    perm   = (int*)alloc(NE * sizeof(int));
  int*    srcs   = (int*)alloc(NE * sizeof(int));
  ushort* eattrs = (ushort*)alloc((size_t)NE * CEC * sizeof(ushort));  // 41 MB CSR-ordered bf16
  ushort* A1     = (ushort*)alloc((size_t)NN * K1 * sizeof(ushort));
  ushort* A23    = (ushort*)alloc((size_t)NN * K23 * sizeof(ushort));
  ushort* Wt1    = (ushort*)alloc((size_t)256 * K1 * sizeof(ushort));
  ushort* Wt2    = (ushort*)alloc((size_t)256 * K23 * sizeof(ushort));
  ushort* Wt3    = (ushort*)alloc((size_t)256 * K23 * sizeof(ushort));
  ushort* xb     = (ushort*)alloc((size_t)NN * CIN * sizeof(ushort));
  ushort* hb     = (ushort*)alloc((size_t)NN * CHID * sizeof(ushort));
  float*  tmp    = (float*)alloc((size_t)NN * CHID * sizeof(float));
  float*  stats  = (float*)alloc(6 * CHID * sizeof(float));  // [layer][sum|sq][256]
  float*  pooled = (float*)alloc((size_t)NB * CHID * sizeof(float));
  float*  counts = (float*)alloc(NB * sizeof(float));
  (void)ws_size; (void)n_in; (void)in_sizes; (void)out_size;

  float* cs1 = stats + 0 * 512, *cq1 = stats + 0 * 512 + 256;
  float* cs2 = stats + 1 * 512, *cq2 = stats + 1 * 512 + 256;
  float* cs3 = stats + 2 * 512, *cq3 = stats + 2 * 512 + 256;

  // CSR + static aggregates
  k_init<<<cdiv(NB * CHID, 256), 256, 0, stream>>>(ptr, pooled, counts, stats);
  k_count<<<1250 + 40, 256, 0, stream>>>(ei, ptr, batch, counts);
  k_scan<<<1, 1024, 0, stream>>>(ptr, pos, degf);
  k_fill<<<1250, 256, 0, stream>>>(ei, pos, perm, srcs);
  k_perm<<<NE / 16, 256, 0, stream>>>((const float4*)eattr, perm, eattrs);
  k_prep<<<1250, 256, 0, stream>>>((const float4*)x, degf, A1, xb);
  k_eag<<<NN / 4, 256, 0, stream>>>(eattrs, xb, ptr, srcs, A1, A23);
  k_wt3<<<1472, 256, 0, stream>>>(W1, W2, W3, Wt1, Wt2, Wt3);

  dim3 ggrid(cdiv(NN, 128), CHID / 64);

  // layer 1
  k_gemm<<<ggrid, 256, 0, stream>>>(A1, Wt1, b1, degf, tmp, cs1, cq1, K1);
  k_bnapply<<<cdiv(NN * 64, 256), 256, 0, stream>>>((const float4*)tmp, cs1, cq1, g1, be1, A23, hb, degf);

  // layer 2
  k_gather256<<<NN / 4, 256, 0, stream>>>(hb, ptr, srcs, A23, 0);
  k_gather256<<<NN / 4, 256, 0, stream>>>(hb, ptr, srcs, A23, 128);
  k_gemm<<<ggrid, 256, 0, stream>>>(A23, Wt2, b2, degf, tmp, cs2, cq2, K23);
  k_bnapply<<<cdiv(NN * 64, 256), 256, 0, stream>>>((const float4*)tmp, cs2, cq2, g2, be2, A23, hb, degf);

  // layer 3
  k_gather256<<<NN / 4, 256, 0, stream>>>(hb, ptr, srcs, A23, 0);
  k_gather256<<<NN / 4, 256, 0, stream>>>(hb, ptr, srcs, A23, 128);
  k_gemm<<<ggrid, 256, 0, stream>>>(A23, Wt3, b3, degf, tmp, cs3, cq3, K23);
  k_poolbn<<<cdiv(NN, 64), 256, 0, stream>>>(tmp, cs3, cq3, g3, be3, batch, pooled);

  // MLP head
  k_mlp<<<NB, 512, 0, stream>>>(pooled, counts, nbr, fc1w, fc1b, fc2w, fc2b, out);
}